// Round 1
// baseline (403.120 us; speedup 1.0000x reference)
//
#include <hip/hip_runtime.h>
#include <math.h>

// ============================================================================
// GTOutputWithPooling2DoubleAttBig  — MI355X (gfx950)
//
// Structure exploited:
//  * window bidaf: only ~25 rows are "real"; other 2023 rows contribute the
//    constant row a_const = softmax(s1) @ q_enc (c=0 there).
//  * b2 = (p_q p_c^T) @ c  via 25x25 M.
//  * pools are never materialized; pooled features dot straight into logits.
//  * only full-L traffic is pool0 over att/mod (~131 MB -> ~21us roofline).
// ============================================================================

constexpr int LL = 2048;
constexpr int GG = 12;
constexpr int QQ = 64;
constexpr int DD = 200;   // 2H
constexpr int AD = 800;   // 8H
constexpr int NW = 25;    // max window rows
constexpr float FNEG = -1e30f;

// ---- workspace layout (float offsets) ----
constexpr size_t OFF_CNT0   = 0;        // [16]
constexpr size_t OFF_S1     = 16;       // [16][64]
constexpr size_t OFF_ACONST = 1040;     // [16][200]
constexpr size_t OFF_PAM    = 4240;     // [16][16][800] att partial max
constexpr size_t OFF_PAS    = 209040;   // partial sum
constexpr size_t OFF_PMM    = 413840;   // [16][16][200] mod partial max
constexpr size_t OFF_PMS    = 465040;
constexpr size_t OFF_PQT    = 516240;   // [192 slots][64][28]  pq^T
constexpr size_t OFF_MT     = 860304;   // [192 slots][25][28]  M^T (MT[l2*28+l]=M[l][l2])
constexpr size_t OFF_ROWS   = 994704;   // int region: [192][26] rows[25]+cnt
constexpr int PQT_STRIDE = 64 * 28;     // 1792
constexpr int MT_STRIDE  = NW * 28;     // 700

__device__ __forceinline__ float block_sum256(float v, float* red) {
  #pragma unroll
  for (int o = 32; o > 0; o >>= 1) v += __shfl_down(v, o, 64);
  if ((threadIdx.x & 63) == 0) red[threadIdx.x >> 6] = v;
  __syncthreads();
  return red[0] + red[1] + red[2] + red[3];
}

// ============================================================================
// K0: per-batch precompute: cnt0, s1[q]=q_enc[q]·qw, a_const=softmax(s1)@q_enc
// ============================================================================
__global__ __launch_bounds__(256) void k_pre(
    const float* __restrict__ q_enc, const float* __restrict__ qwv,
    const float* __restrict__ biasp, const int* __restrict__ q_mask,
    const int* __restrict__ mask, float* __restrict__ ws) {
  const int b = blockIdx.x, t = threadIdx.x;
  __shared__ float qe[QQ][204];
  __shared__ float pqc[QQ];
  __shared__ float s1S[QQ];
  __shared__ float red[4];

  int c = 0;
  for (int l = t; l < LL; l += 256) c += (mask[b * LL + l] > 0) ? 1 : 0;
  float cf = block_sum256((float)c, red);
  if (t == 0) ws[OFF_CNT0 + b] = cf;

  for (int i = t; i < QQ * DD; i += 256) {
    int q = i / DD, d = i - q * DD;
    qe[q][d] = q_enc[((size_t)b * QQ + q) * DD + d];
  }
  __syncthreads();

  if (t < QQ) {
    float a = 0.f;
    for (int d = 0; d < DD; ++d) a += qe[t][d] * qwv[d];
    s1S[t] = a;
    ws[OFF_S1 + b * QQ + t] = a;
  }
  __syncthreads();

  if (t == 0) {
    const float bv = biasp[0];
    float m = -3.0e38f;
    for (int q = 0; q < QQ; ++q) {
      float v = (q_mask[b * QQ + q] > 0) ? (s1S[q] + bv) : FNEG;
      m = fmaxf(m, v);
    }
    float sum = 0.f;
    for (int q = 0; q < QQ; ++q) {
      float v = (q_mask[b * QQ + q] > 0) ? (s1S[q] + bv) : FNEG;
      float e = expf(v - m);
      pqc[q] = e; sum += e;
    }
    float inv = 1.f / sum;
    for (int q = 0; q < QQ; ++q) pqc[q] *= inv;
  }
  __syncthreads();

  if (t < DD) {
    float a = 0.f;
    for (int q = 0; q < QQ; ++q) a += pqc[q] * qe[q][t];
    ws[OFF_ACONST + b * DD + t] = a;
  }
}

// ============================================================================
// K1a/K1b: pool0 partials. Coalesced: thread = float4 column, loop 128 rows.
// ============================================================================
__global__ __launch_bounds__(256) void k_pool_att(const float* __restrict__ att,
                                                  float* __restrict__ ws) {
  const int ch = blockIdx.x, b = blockIdx.y, t = threadIdx.x;
  if (t >= 200) return;  // 800/4 float4 columns
  const float4* p = (const float4*)(att + ((size_t)b * LL + (size_t)ch * 128) * AD) + t;
  float4 v = *p;
  float m0 = v.x, m1 = v.y, m2 = v.z, m3 = v.w;
  float s0 = v.x, s1 = v.y, s2 = v.z, s3 = v.w;
  for (int r = 1; r < 128; ++r) {
    v = p[(size_t)r * 200];
    m0 = fmaxf(m0, v.x); m1 = fmaxf(m1, v.y); m2 = fmaxf(m2, v.z); m3 = fmaxf(m3, v.w);
    s0 += v.x; s1 += v.y; s2 += v.z; s3 += v.w;
  }
  float4 mx = make_float4(m0, m1, m2, m3);
  float4 sm = make_float4(s0, s1, s2, s3);
  ((float4*)(ws + OFF_PAM))[(size_t)(b * 16 + ch) * 200 + t] = mx;
  ((float4*)(ws + OFF_PAS))[(size_t)(b * 16 + ch) * 200 + t] = sm;
}

__global__ __launch_bounds__(64) void k_pool_mod(const float* __restrict__ mod,
                                                 float* __restrict__ ws) {
  const int ch = blockIdx.x, b = blockIdx.y, t = threadIdx.x;
  if (t >= 50) return;  // 200/4 float4 columns
  const float4* p = (const float4*)(mod + ((size_t)b * LL + (size_t)ch * 128) * DD) + t;
  float4 v = *p;
  float m0 = v.x, m1 = v.y, m2 = v.z, m3 = v.w;
  float s0 = v.x, s1 = v.y, s2 = v.z, s3 = v.w;
  for (int r = 1; r < 128; ++r) {
    v = p[(size_t)r * 50];
    m0 = fmaxf(m0, v.x); m1 = fmaxf(m1, v.y); m2 = fmaxf(m2, v.z); m3 = fmaxf(m3, v.w);
    s0 += v.x; s1 += v.y; s2 += v.z; s3 += v.w;
  }
  float4 mx = make_float4(m0, m1, m2, m3);
  float4 sm = make_float4(s0, s1, s2, s3);
  ((float4*)(ws + OFF_PMM))[(size_t)(b * 16 + ch) * 50 + t] = mx;
  ((float4*)(ws + OFF_PMS))[(size_t)(b * 16 + ch) * 50 + t] = sm;
}

// ============================================================================
// K2 (phaseA): per (b, x) bidaf front half. x==0: gap-row bidaf (c_mask=ones).
// x in 1..11: window bidaf for gid=gaps[b,x]. Produces pq^T, M^T, rows+cnt.
// s2 trick: c-rows via uniform s_loads of raw mod; cqw folded into LDS q_enc.
// ============================================================================
__global__ __launch_bounds__(256) void k_phaseA(
    const float* __restrict__ mod, const float* __restrict__ q_enc,
    const int* __restrict__ gaps, const int* __restrict__ mask,
    const int* __restrict__ q_mask, const float* __restrict__ cwv,
    const float* __restrict__ cqw, const float* __restrict__ biasp,
    float* __restrict__ ws) {
  const int x = blockIdx.x, b = blockIdx.y, t = threadIdx.x;
  __shared__ float qec[QQ][204];     // cqw-folded q_enc
  __shared__ float sS[NW][68];
  __shared__ float pqS[NW][68];
  __shared__ float pcS[NW][68];
  __shared__ float s0S[NW];
  __shared__ int rowsS[NW];
  __shared__ int cntS;

  if (t == 0) {
    int c = 0;
    if (x == 0) {
      for (int g = 0; g < GG; ++g) rowsS[c++] = gaps[b * GG + g];
    } else {
      int gid = gaps[b * GG + x];
      int lo = gid - 12; if (lo < 0) lo = 0;
      int hi = gid + 12; if (hi > LL - 1) hi = LL - 1;
      for (int l = lo; l <= hi; ++l)
        if (mask[b * LL + l] > 0) rowsS[c++] = l;
    }
    int cr = (c > 0) ? rowsS[c - 1] : 0;
    for (int i = c; i < NW; ++i) rowsS[i] = cr;  // clamp-pad (real rows)
    cntS = c;
  }
  // stage cqw-folded q_enc (coalesced)
  for (int i = t; i < QQ * DD; i += 256) {
    int q = i / DD, d = i - q * DD;
    qec[q][d] = q_enc[((size_t)b * QQ + q) * DD + d] * cqw[d];
  }
  __syncthreads();
  const int cnt = cntS;

  // s0[r] = c_row · c_weight  (t<25, per-lane row, float4 global reads)
  if (t < NW) {
    float a = 0.f;
    if (t < cnt) {
      const float4* cr4 = (const float4*)(mod + ((size_t)b * LL + rowsS[t]) * DD);
      const float4* cw4 = (const float4*)cwv;
      for (int j = 0; j < 50; ++j) {
        float4 cv = cr4[j], wv = cw4[j];
        a += cv.x * wv.x + cv.y * wv.y + cv.z * wv.z + cv.w * wv.w;
      }
    }
    s0S[t] = a;
  }

  // s2: wave w owns l-chunk; lane = q. c via uniform s_loads, qec via b128.
  {
    const int w = t >> 6, q = t & 63;
    const int l0 = (cnt * w) >> 2;
    const int l1 = (cnt * (w + 1)) >> 2;
    const int nl = l1 - l0;
    const float* crow[7];
    float accl[7];
    #pragma unroll
    for (int i = 0; i < 7; ++i) {
      accl[i] = 0.f;
      int li = l0 + ((i < nl) ? i : 0);
      int row = __builtin_amdgcn_readfirstlane(rowsS[li]);
      crow[i] = mod + ((size_t)b * LL + row) * DD;
    }
    for (int d = 0; d < DD; d += 4) {
      const float4 qv = *(const float4*)&qec[q][d];
      #pragma unroll
      for (int i = 0; i < 7; ++i) {
        if (i < nl) {
          const float* cr = crow[i];
          accl[i] += cr[d] * qv.x + cr[d + 1] * qv.y + cr[d + 2] * qv.z + cr[d + 3] * qv.w;
        }
      }
    }
    const float s1q = ws[OFF_S1 + b * QQ + q];
    const float bv = biasp[0];
    #pragma unroll
    for (int i = 0; i < 7; ++i)
      if (i < nl) sS[l0 + i][q] = accl[i] + s1q + bv;
  }
  __syncthreads();

  const int slot = b * GG + x;
  float* pqT = ws + OFF_PQT + (size_t)slot * PQT_STRIDE;

  // row softmax (p_q) on t<25, q_mask applied; write pq^T (zero-padded rows)
  if (t < NW) {
    const int r = t;
    if (r < cnt) {
      const float sr0 = s0S[r];
      float m = -3.0e38f;
      for (int q = 0; q < QQ; ++q) {
        float v = (q_mask[b * QQ + q] > 0) ? (sS[r][q] + sr0) : FNEG;
        m = fmaxf(m, v);
      }
      float sum = 0.f;
      for (int q = 0; q < QQ; ++q) {
        float v = (q_mask[b * QQ + q] > 0) ? (sS[r][q] + sr0) : FNEG;
        float e = expf(v - m);
        pqS[r][q] = e; sum += e;
      }
      float inv = 1.f / sum;
      for (int q = 0; q < QQ; ++q) {
        float p = pqS[r][q] * inv;
        pqS[r][q] = p;
        pqT[q * 28 + r] = p;
      }
    } else {
      for (int q = 0; q < QQ; ++q) { pqS[r][q] = 0.f; pqT[q * 28 + r] = 0.f; }
    }
  }
  // column softmax (p_c) over window rows on t in [64,128)
  if (t >= 64 && t < 128) {
    const int q = t - 64;
    float m = -3.0e38f;
    for (int r = 0; r < NW; ++r)
      if (r < cnt) m = fmaxf(m, sS[r][q] + s0S[r]);
    float sum = 0.f;
    for (int r = 0; r < NW; ++r) {
      float e = 0.f;
      if (r < cnt) { e = expf(sS[r][q] + s0S[r] - m); sum += e; }
      pcS[r][q] = e;
    }
    float inv = (sum > 0.f) ? (1.f / sum) : 0.f;
    for (int r = 0; r < NW; ++r) pcS[r][q] *= inv;
  }
  __syncthreads();

  // M[l][l2] = sum_q pq[l][q]*pc[l2][q]; wave-parallel entries, lane=q reduce.
  float* MT = ws + OFF_MT + (size_t)slot * MT_STRIDE;
  {
    const int w = t >> 6, lane = t & 63;
    for (int e = w; e < NW * NW; e += 4) {
      int l = e / NW, l2 = e - l * NW;
      float v = 0.f;
      if (l < cnt && l2 < cnt) v = pqS[l][lane] * pcS[l2][lane];
      #pragma unroll
      for (int o = 32; o > 0; o >>= 1) v += __shfl_down(v, o, 64);
      if (lane == 0) MT[l2 * 28 + l] = v;
    }
  }
  if (t == 0) {
    int* rws = (int*)(ws + OFF_ROWS) + slot * 26;
    for (int i = 0; i < NW; ++i) rws[i] = rowsS[i];
    rws[NW] = cnt;
  }
}

// ============================================================================
// K3 (phaseB): per (b, x) logit. x==0: pool0 dots + gap features g=0.
// x>=1: window pools (a/ca/cb2 via s_load pq^T / M^T; acc[25] in registers)
//       + att window pool + gap features g=x. Writes logits[b,x].
// ============================================================================
__global__ __launch_bounds__(256) void k_phaseB(
    const float* __restrict__ mod, const float* __restrict__ att,
    const float* __restrict__ q_enc, const int* __restrict__ gaps,
    const float* __restrict__ wA,  const float* __restrict__ bA,
    const float* __restrict__ wM,  const float* __restrict__ bM,
    const float* __restrict__ wA2, const float* __restrict__ bA2,
    const float* __restrict__ wAs, const float* __restrict__ bAs,
    const float* __restrict__ wMs, const float* __restrict__ bMs,
    const float* __restrict__ wA2s,const float* __restrict__ bA2s,
    const float* __restrict__ ws, float* __restrict__ out) {
  const int x = blockIdx.x, b = blockIdx.y, t = threadIdx.x;
  __shared__ float red[4];

  const float* wa  = x ? wA  : wAs;
  const float* wm  = x ? wM  : wMs;
  const float* wa2 = x ? wA2 : wA2s;
  const float biassum = x ? (bA[0] + bM[0] + bA2[0]) : (bAs[0] + bMs[0] + bA2s[0]);

  const int slot0 = b * GG;  // gap-bidaf slot
  const float* pqTg = ws + OFF_PQT + (size_t)slot0 * PQT_STRIDE;
  const float* MTg  = ws + OFF_MT  + (size_t)slot0 * MT_STRIDE;
  const int gid = gaps[b * GG + x];

  float acc = 0.f;

  if (x == 0) {
    // ---- pool0 contributions ----
    const float inv0 = 1.f / ws[OFF_CNT0 + b];
    for (int f = t; f < AD; f += 256) {
      float mx = -3.0e38f, sm = 0.f;
      #pragma unroll
      for (int c = 0; c < 16; ++c) {
        mx = fmaxf(mx, ws[OFF_PAM + (size_t)(b * 16 + c) * AD + f]);
        sm += ws[OFF_PAS + (size_t)(b * 16 + c) * AD + f];
      }
      acc += mx * wa[AD + f] + sm * inv0 * wa[2 * AD + f];
    }
    if (t < DD) {
      const int d = t;
      float mx = -3.0e38f, sm = 0.f;
      #pragma unroll
      for (int c = 0; c < 16; ++c) {
        mx = fmaxf(mx, ws[OFF_PMM + (size_t)(b * 16 + c) * DD + d]);
        sm += ws[OFF_PMS + (size_t)(b * 16 + c) * DD + d];
      }
      acc += mx * wm[DD + d] + sm * inv0 * wm[2 * DD + d];
    }
    // ---- gap features, g=0 (att2 pools are zeros) ----
    if (t < DD) {
      const int d = t;
      const float cg = mod[((size_t)b * LL + gid) * DD + d];
      float aG = 0.f;
      for (int q = 0; q < QQ; ++q)
        aG += pqTg[q * 28 + 0] * q_enc[((size_t)b * QQ + q) * DD + d];
      float b2G = 0.f;
      #pragma unroll
      for (int r2 = 0; r2 < GG; ++r2)
        b2G += MTg[r2 * 28 + 0] * mod[((size_t)b * LL + gaps[b * GG + r2]) * DD + d];
      acc += cg * (wa2[d] + wm[d]) + aG * wa2[DD + d]
           + cg * aG * wa2[2 * DD + d] + cg * b2G * wa2[3 * DD + d];
    }
    const float* arow = att + ((size_t)b * LL + gid) * AD;
    for (int f = t; f < AD; f += 256) acc += arow[f] * wa[f];

    const float tot = block_sum256(acc, red);
    if (t == 0) out[b * GG + 0] = tot + biassum;
    return;
  }

  // ---- x >= 1: window ----
  const int slot = b * GG + x;
  const int* rwsp = (const int*)(ws + OFF_ROWS) + slot * 26;
  int rr[NW];
  #pragma unroll
  for (int r = 0; r < NW; ++r) rr[r] = rwsp[r];
  const int cnt = rwsp[NW];
  const float invc = 1.f / (float)cnt;
  const float* pqT = ws + OFF_PQT + (size_t)slot * PQT_STRIDE;
  const float* MT  = ws + OFF_MT  + (size_t)slot * MT_STRIDE;

  if (t < DD) {
    const int d = t;
    float cR[NW];
    #pragma unroll
    for (int r = 0; r < NW; ++r)
      cR[r] = mod[((size_t)b * LL + rr[r]) * DD + d];

    // a[r,d] for window rows + aG (gap-bidaf row x), shared q_enc loads
    float aacc[NW];
    #pragma unroll
    for (int r = 0; r < NW; ++r) aacc[r] = 0.f;
    float aG = 0.f;
    for (int q = 0; q < QQ; ++q) {
      const float vq = q_enc[((size_t)b * QQ + q) * DD + d];
      const float* pcol = pqT + q * 28;       // uniform -> s_loads
      #pragma unroll
      for (int r = 0; r < NW; ++r) aacc[r] += pcol[r] * vq;
      aG += pqTg[q * 28 + x] * vq;
    }

    const float ac = ws[OFF_ACONST + b * DD + d];
    float maxc = 0.f, sumc = 0.f, maxa = ac, suma = 0.f, maxca = 0.f, sumca = 0.f;
    #pragma unroll
    for (int r = 0; r < NW; ++r) {
      if (r < cnt) {
        const float c = cR[r], a = aacc[r];
        maxc = fmaxf(maxc, c); sumc += c;
        maxa = fmaxf(maxa, a); suma += a;
        const float ca = c * a; maxca = fmaxf(maxca, ca); sumca += ca;
      }
    }
    suma += (float)(LL - cnt) * ac;   // constant rows outside window

    // b2[r,d] = sum_r2 M[r][r2]*c[r2,d]  (reuse aacc)
    #pragma unroll
    for (int r = 0; r < NW; ++r) aacc[r] = 0.f;
    #pragma unroll
    for (int r2 = 0; r2 < NW; ++r2) {
      const float cv = cR[r2];
      const float* mrow = MT + r2 * 28;       // uniform -> s_loads
      #pragma unroll
      for (int r = 0; r < NW; ++r) aacc[r] += mrow[r] * cv;
    }
    float maxcb = 0.f, sumcb = 0.f;
    #pragma unroll
    for (int r = 0; r < NW; ++r) {
      if (r < cnt) {
        const float cb = cR[r] * aacc[r];
        maxcb = fmaxf(maxcb, cb); sumcb += cb;
      }
    }

    // window-pool dot contributions (mod pool + att2 pool)
    acc += maxc * (wm[DD + d] + wa2[AD + d]) + sumc * invc * (wm[2 * DD + d] + wa2[2 * AD + d]);
    acc += maxa * wa2[AD + DD + d]     + suma  * invc * wa2[2 * AD + DD + d];
    acc += maxca * wa2[AD + 2 * DD + d] + sumca * invc * wa2[2 * AD + 2 * DD + d];
    acc += maxcb * wa2[AD + 3 * DD + d] + sumcb * invc * wa2[2 * AD + 3 * DD + d];

    // gap features for g = x
    float cgR[GG];
    #pragma unroll
    for (int r2 = 0; r2 < GG; ++r2)
      cgR[r2] = mod[((size_t)b * LL + gaps[b * GG + r2]) * DD + d];
    float b2G = 0.f;
    #pragma unroll
    for (int r2 = 0; r2 < GG; ++r2) b2G += MTg[r2 * 28 + x] * cgR[r2];
    const float cg = mod[((size_t)b * LL + gid) * DD + d];
    acc += cg * (wa2[d] + wm[d]) + aG * wa2[DD + d]
         + cg * aG * wa2[2 * DD + d] + cg * b2G * wa2[3 * DD + d];
  }

  // att window pool + att gap-row dot (all 256 threads)
  const float* arow = att + ((size_t)b * LL + gid) * AD;
  for (int f = t; f < AD; f += 256) {
    float mx = 0.f, sm = 0.f;
    #pragma unroll
    for (int r = 0; r < NW; ++r) {
      if (r < cnt) {
        const float v = att[((size_t)b * LL + rr[r]) * AD + f];
        mx = fmaxf(mx, v); sm += v;
      }
    }
    acc += mx * wa[AD + f] + sm * invc * wa[2 * AD + f] + arow[f] * wa[f];
  }

  const float tot = block_sum256(acc, red);
  if (t == 0) out[b * GG + x] = tot + biassum;
}

// ============================================================================
extern "C" void kernel_launch(void* const* d_in, const int* in_sizes, int n_in,
                              void* d_out, int out_size, void* d_ws, size_t ws_size,
                              hipStream_t stream) {
  const float* att    = (const float*)d_in[0];
  const float* mod    = (const float*)d_in[1];
  const int*   gaps   = (const int*)  d_in[2];
  const int*   mask   = (const int*)  d_in[3];
  const float* q_enc  = (const float*)d_in[4];
  const int*   q_mask = (const int*)  d_in[5];
  const float* cwv    = (const float*)d_in[6];
  const float* qwv    = (const float*)d_in[7];
  const float* cqw    = (const float*)d_in[8];
  const float* biasp  = (const float*)d_in[9];
  const float* wA     = (const float*)d_in[10];
  const float* bA     = (const float*)d_in[11];
  const float* wM     = (const float*)d_in[12];
  const float* bM     = (const float*)d_in[13];
  const float* wA2    = (const float*)d_in[14];
  const float* bA2    = (const float*)d_in[15];
  const float* wAs    = (const float*)d_in[16];
  const float* bAs    = (const float*)d_in[17];
  const float* wMs    = (const float*)d_in[18];
  const float* bMs    = (const float*)d_in[19];
  const float* wA2s   = (const float*)d_in[20];
  const float* bA2s   = (const float*)d_in[21];
  float* out = (float*)d_out;
  float* ws  = (float*)d_ws;

  hipLaunchKernelGGL(k_pre, dim3(16), dim3(256), 0, stream,
                     q_enc, qwv, biasp, q_mask, mask, ws);
  hipLaunchKernelGGL(k_pool_att, dim3(16, 16), dim3(256), 0, stream, att, ws);
  hipLaunchKernelGGL(k_pool_mod, dim3(16, 16), dim3(64), 0, stream, mod, ws);
  hipLaunchKernelGGL(k_phaseA, dim3(12, 16), dim3(256), 0, stream,
                     mod, q_enc, gaps, mask, q_mask, cwv, cqw, biasp, ws);
  hipLaunchKernelGGL(k_phaseB, dim3(12, 16), dim3(256), 0, stream,
                     mod, att, q_enc, gaps,
                     wA, bA, wM, bM, wA2, bA2, wAs, bAs, wMs, bMs, wA2s, bA2s,
                     ws, out);
}

// Round 2
// 306.210 us; speedup vs baseline: 1.3165x; 1.3165x over previous
//
#include <hip/hip_runtime.h>
#include <math.h>

// ============================================================================
// GTOutputWithPooling2DoubleAttBig — MI355X (gfx950)
//
// R1 restructure: phaseA+phaseB+pre merged into ONE kernel per (b,x) with all
// bidaf state in LDS (no global ws round-trips, no serial-lane sections).
//  * rows: window ≤25 (ballot-compacted) + 12 gap rows; scores/softmax/M all
//    LDS-resident; gap bidaf recomputed per block (300 KFLOP) to kill the
//    cross-block dependency.
//  * a_const handled as "row 26" of the pq set (pq = softmax(s1)).
//  * qeS uses a +16B-per-8-rows bump so stride-816B b128 reads are
//    conflict-free.
//  * pool0 partials still via two streaming kernels (HBM-bound, ~131 MB).
// ============================================================================

constexpr int LL = 2048;
constexpr int GG = 12;
constexpr int QQ = 64;
constexpr int DD = 200;   // 2H
constexpr int AD = 800;   // 8H
constexpr int NW = 25;    // max window rows
constexpr float FNEG = -1e30f;

// ---- workspace layout (float offsets): pool0 partials only ----
constexpr size_t OFF_PAM = 0;         // [16][16][800] att partial max
constexpr size_t OFF_PAS = 204800;    // att partial sum
constexpr size_t OFF_PMM = 409600;    // [16][16][200] mod partial max
constexpr size_t OFF_PMS = 460800;    // mod partial sum

#define IDX_QE(q, d) ((q) * 204 + (((q) >> 3) << 2) + (d))

#define DOT27(ACC, PR, V)                                                      \
  {                                                                            \
    const float4 _p0 = PR[0], _p1 = PR[1], _p2 = PR[2], _p3 = PR[3],           \
                 _p4 = PR[4], _p5 = PR[5], _p6 = PR[6];                        \
    ACC[0] += _p0.x * V;  ACC[1] += _p0.y * V;  ACC[2] += _p0.z * V;           \
    ACC[3] += _p0.w * V;  ACC[4] += _p1.x * V;  ACC[5] += _p1.y * V;           \
    ACC[6] += _p1.z * V;  ACC[7] += _p1.w * V;  ACC[8] += _p2.x * V;           \
    ACC[9] += _p2.y * V;  ACC[10] += _p2.z * V; ACC[11] += _p2.w * V;          \
    ACC[12] += _p3.x * V; ACC[13] += _p3.y * V; ACC[14] += _p3.z * V;          \
    ACC[15] += _p3.w * V; ACC[16] += _p4.x * V; ACC[17] += _p4.y * V;          \
    ACC[18] += _p4.z * V; ACC[19] += _p4.w * V; ACC[20] += _p5.x * V;          \
    ACC[21] += _p5.y * V; ACC[22] += _p5.z * V; ACC[23] += _p5.w * V;          \
    ACC[24] += _p6.x * V; ACC[25] += _p6.y * V; ACC[26] += _p6.z * V;          \
  }

#define DOT25(ACC, PR, V)                                                      \
  {                                                                            \
    const float4 _p0 = PR[0], _p1 = PR[1], _p2 = PR[2], _p3 = PR[3],           \
                 _p4 = PR[4], _p5 = PR[5], _p6 = PR[6];                        \
    ACC[0] += _p0.x * V;  ACC[1] += _p0.y * V;  ACC[2] += _p0.z * V;           \
    ACC[3] += _p0.w * V;  ACC[4] += _p1.x * V;  ACC[5] += _p1.y * V;           \
    ACC[6] += _p1.z * V;  ACC[7] += _p1.w * V;  ACC[8] += _p2.x * V;           \
    ACC[9] += _p2.y * V;  ACC[10] += _p2.z * V; ACC[11] += _p2.w * V;          \
    ACC[12] += _p3.x * V; ACC[13] += _p3.y * V; ACC[14] += _p3.z * V;          \
    ACC[15] += _p3.w * V; ACC[16] += _p4.x * V; ACC[17] += _p4.y * V;          \
    ACC[18] += _p4.z * V; ACC[19] += _p4.w * V; ACC[20] += _p5.x * V;          \
    ACC[21] += _p5.y * V; ACC[22] += _p5.z * V; ACC[23] += _p5.w * V;          \
    ACC[24] += _p6.x * V;                                                      \
  }

__device__ __forceinline__ float block_sum256(float v, float* red) {
  #pragma unroll
  for (int o = 32; o > 0; o >>= 1) v += __shfl_down(v, o, 64);
  if ((threadIdx.x & 63) == 0) red[threadIdx.x >> 6] = v;
  __syncthreads();
  const float r = red[0] + red[1] + red[2] + red[3];
  __syncthreads();
  return r;
}

// ============================================================================
// pool0 partials: coalesced float4 column streaming, 16 L-chunks per batch.
// ============================================================================
__global__ __launch_bounds__(256) void k_pool_att(const float* __restrict__ att,
                                                  float* __restrict__ ws) {
  const int ch = blockIdx.x, b = blockIdx.y, t = threadIdx.x;
  if (t >= 200) return;
  const float4* p = (const float4*)(att + ((size_t)b * LL + (size_t)ch * 128) * AD) + t;
  float4 v = *p;
  float m0 = v.x, m1 = v.y, m2 = v.z, m3 = v.w;
  float s0 = v.x, s1 = v.y, s2 = v.z, s3 = v.w;
  for (int r = 1; r < 128; ++r) {
    v = p[(size_t)r * 200];
    m0 = fmaxf(m0, v.x); m1 = fmaxf(m1, v.y); m2 = fmaxf(m2, v.z); m3 = fmaxf(m3, v.w);
    s0 += v.x; s1 += v.y; s2 += v.z; s3 += v.w;
  }
  ((float4*)(ws + OFF_PAM))[(size_t)(b * 16 + ch) * 200 + t] = make_float4(m0, m1, m2, m3);
  ((float4*)(ws + OFF_PAS))[(size_t)(b * 16 + ch) * 200 + t] = make_float4(s0, s1, s2, s3);
}

__global__ __launch_bounds__(64) void k_pool_mod(const float* __restrict__ mod,
                                                 float* __restrict__ ws) {
  const int ch = blockIdx.x, b = blockIdx.y, t = threadIdx.x;
  if (t >= 50) return;
  const float4* p = (const float4*)(mod + ((size_t)b * LL + (size_t)ch * 128) * DD) + t;
  float4 v = *p;
  float m0 = v.x, m1 = v.y, m2 = v.z, m3 = v.w;
  float s0 = v.x, s1 = v.y, s2 = v.z, s3 = v.w;
  for (int r = 1; r < 128; ++r) {
    v = p[(size_t)r * 50];
    m0 = fmaxf(m0, v.x); m1 = fmaxf(m1, v.y); m2 = fmaxf(m2, v.z); m3 = fmaxf(m3, v.w);
    s0 += v.x; s1 += v.y; s2 += v.z; s3 += v.w;
  }
  ((float4*)(ws + OFF_PMM))[(size_t)(b * 16 + ch) * 50 + t] = make_float4(m0, m1, m2, m3);
  ((float4*)(ws + OFF_PMS))[(size_t)(b * 16 + ch) * 50 + t] = make_float4(s0, s1, s2, s3);
}

// ============================================================================
// k_main: per (b,x) — full bidaf (window + gap) + pools + logit, all in LDS.
// ============================================================================
__global__ __launch_bounds__(256) void k_main(
    const float* __restrict__ att, const float* __restrict__ mod,
    const int* __restrict__ gaps, const int* __restrict__ mask,
    const float* __restrict__ q_enc, const int* __restrict__ q_mask,
    const float* __restrict__ cwv, const float* __restrict__ qwv,
    const float* __restrict__ cqw, const float* __restrict__ biasp,
    const float* __restrict__ wA,  const float* __restrict__ bA,
    const float* __restrict__ wM,  const float* __restrict__ bM,
    const float* __restrict__ wA2, const float* __restrict__ bA2,
    const float* __restrict__ wAs, const float* __restrict__ bAs,
    const float* __restrict__ wMs, const float* __restrict__ bMs,
    const float* __restrict__ wA2s,const float* __restrict__ bA2s,
    const float* __restrict__ ws, float* __restrict__ out) {

  const int x = blockIdx.x, b = blockIdx.y, t = threadIdx.x;
  const int w = t >> 6, lane = t & 63;

  __shared__ float qeS[13088];       // IDX_QE layout (bank-bumped)
  __shared__ float cA[37][200];      // rows 0..24 window (x>=1), 25..36 gap
  __shared__ float sA[37][68];       // scores (s0+s1+s2+bias)
  __shared__ float pqS[27][68];      // row softmax: 0..24 win, 25 gap-row-x, 26 const
  __shared__ float pqT[64][28];      // transposed pq for the a-pass
  __shared__ float pcA[37][68];      // col softmax: 0..24 win, 25..36 gap
  __shared__ float MTS[25][28];      // MTS[r2][r] = M[r][r2] (window)
  __shared__ float MgS[12];          // Mg[x][r2] (gap)
  __shared__ float s0A[40], s1S[64];
  __shared__ float cwS[200], qwS[200], cqwS[200];
  __shared__ int   qmS[64];
  __shared__ int   rowsS[40];
  __shared__ int   cntS, gidS;
  __shared__ float cnt0S, bvS;
  __shared__ float red[4];

  // ---------------- S1: small stages + window-row compaction ----------------
  if (t < 50)              ((float4*)cwS)[t]       = ((const float4*)cwv)[t];
  if (t >= 64 && t < 114)  ((float4*)qwS)[t - 64]  = ((const float4*)qwv)[t - 64];
  if (t >= 128 && t < 178) ((float4*)cqwS)[t - 128] = ((const float4*)cqw)[t - 128];
  if (t >= 50 && t < 66)   ((int4*)qmS)[t - 50]    = ((const int4*)(q_mask + b * QQ))[t - 50];
  if (t == 66) bvS = biasp[0];
  if (w == 3) {
    const int gid = gaps[b * GG + x];
    if (lane == 0) gidS = gid;
    if (lane >= 32 && lane < 44) rowsS[NW + lane - 32] = gaps[b * GG + (lane - 32)];
    bool ok = false; int pos = 0;
    if (x > 0 && lane < NW) {
      const int lo = max(gid - 12, 0), hi = min(gid + 12, LL - 1);
      pos = lo + lane;
      ok = (pos <= hi) && (mask[(size_t)b * LL + pos] > 0);
    }
    const unsigned long long bal = __ballot(ok);
    if (lane < NW) rowsS[lane] = gid;  // pad default (valid row)
    if (ok) rowsS[__popcll(bal & ((1ull << lane) - 1ull))] = pos;
    if (lane == 0) cntS = (x > 0) ? __popcll(bal) : 0;
  }
  __syncthreads();

  // ---------------- S2: stage q_enc + c rows (+cnt0 for x==0) --------------
  {
    const float4* qe4 = (const float4*)(q_enc + (size_t)b * QQ * DD);
    for (int i = t; i < QQ * DD / 4; i += 256) {
      const int q = i / 50, dc = (i - q * 50) * 4;
      *(float4*)&qeS[IDX_QE(q, dc)] = qe4[i];
    }
    const int n4 = (x == 0) ? (GG * 50) : (37 * 50);
    const int rB = (x == 0) ? NW : 0;
    for (int i = t; i < n4; i += 256) {
      const int rr = i / 50, dc = (i - rr * 50) * 4;
      *(float4*)&cA[rB + rr][dc] =
          *(const float4*)(mod + ((size_t)b * LL + rowsS[rB + rr]) * DD + dc);
    }
    if (x == 0) {
      int cm = 0;
      for (int l = t; l < LL; l += 256) cm += (mask[(size_t)b * LL + l] > 0) ? 1 : 0;
      const float cf = block_sum256((float)cm, red);
      if (t == 0) cnt0S = cf;
    }
  }
  __syncthreads();

  // ---------------- S3: s1[q] (4 lanes/q) and s0[r] ------------------------
  {
    const int q = t >> 2, j2 = t & 3;
    float a = 0.f;
    for (int d = j2; d < DD; d += 4) a += qeS[IDX_QE(q, d)] * qwS[d];
    a += __shfl_xor(a, 1, 64);
    a += __shfl_xor(a, 2, 64);
    if (j2 == 0) s1S[q] = a;
  }
  if (t < 37) {
    float a = 0.f;
    const float4* cr4 = (const float4*)&cA[t][0];
    const float4* cw4 = (const float4*)cwS;
    for (int k = 0; k < 50; ++k) {
      const float4 cv = cr4[k], wv = cw4[k];
      a += cv.x * wv.x + cv.y * wv.y + cv.z * wv.z + cv.w * wv.w;
    }
    s0A[t] = a;
  }
  __syncthreads();

  // ---------------- s2: scores, lane=q, 5-row register blocks --------------
  {
    const int q = lane;
    const int rBase = (x == 0) ? NW : 0;
    const int nR = (x == 0) ? GG : 37;
    const float baseq = s1S[q] + bvS;
    const float* qp = &qeS[IDX_QE(q, 0)];
    #pragma unroll
    for (int g = 0; g < 2; ++g) {
      const int iB = w + 20 * g;
      if (iB < nR) {
        const int i1 = (iB + 4  < nR) ? iB + 4  : iB;
        const int i2 = (iB + 8  < nR) ? iB + 8  : iB;
        const int i3 = (iB + 12 < nR) ? iB + 12 : iB;
        const int i4 = (iB + 16 < nR) ? iB + 16 : iB;
        const float* c0 = &cA[rBase + iB][0];
        const float* c1 = &cA[rBase + i1][0];
        const float* c2 = &cA[rBase + i2][0];
        const float* c3 = &cA[rBase + i3][0];
        const float* c4 = &cA[rBase + i4][0];
        float a0 = 0.f, a1 = 0.f, a2 = 0.f, a3 = 0.f, a4 = 0.f;
        for (int d = 0; d < DD; d += 4) {
          const float4 qv = *(const float4*)(qp + d);
          const float4 wv = *(const float4*)&cqwS[d];
          float4 qc;
          qc.x = qv.x * wv.x; qc.y = qv.y * wv.y; qc.z = qv.z * wv.z; qc.w = qv.w * wv.w;
          float4 v;
          v = *(const float4*)(c0 + d); a0 += v.x*qc.x + v.y*qc.y + v.z*qc.z + v.w*qc.w;
          v = *(const float4*)(c1 + d); a1 += v.x*qc.x + v.y*qc.y + v.z*qc.z + v.w*qc.w;
          v = *(const float4*)(c2 + d); a2 += v.x*qc.x + v.y*qc.y + v.z*qc.z + v.w*qc.w;
          v = *(const float4*)(c3 + d); a3 += v.x*qc.x + v.y*qc.y + v.z*qc.z + v.w*qc.w;
          v = *(const float4*)(c4 + d); a4 += v.x*qc.x + v.y*qc.y + v.z*qc.z + v.w*qc.w;
        }
        sA[rBase + iB][q] = a0 + s0A[rBase + iB] + baseq;
        if (iB + 4  < nR) sA[rBase + i1][q] = a1 + s0A[rBase + i1] + baseq;
        if (iB + 8  < nR) sA[rBase + i2][q] = a2 + s0A[rBase + i2] + baseq;
        if (iB + 12 < nR) sA[rBase + i3][q] = a3 + s0A[rBase + i3] + baseq;
        if (iB + 16 < nR) sA[rBase + i4][q] = a4 + s0A[rBase + i4] + baseq;
      }
    }
  }
  __syncthreads();

  // ---------------- softmaxes: rows (8-lane groups) + cols -----------------
  {
    const int grp = t >> 3, j = t & 7;
    if (grp < 27) {
      const bool zero = (grp < NW) && (grp >= cntS);
      const int sr = (grp < NW) ? grp : NW + x;  // grp==26 doesn't use sr
      if (zero) {
        #pragma unroll
        for (int k = 0; k < 8; ++k) {
          const int q = j * 8 + k;
          pqS[grp][q] = 0.f; pqT[q][grp] = 0.f;
        }
      } else {
        float v[8];
        #pragma unroll
        for (int k = 0; k < 8; ++k) {
          const int q = j * 8 + k;
          const float s = (grp == 26) ? (s1S[q] + bvS) : sA[sr][q];
          v[k] = (qmS[q] > 0) ? s : FNEG;
        }
        float m = v[0];
        #pragma unroll
        for (int k = 1; k < 8; ++k) m = fmaxf(m, v[k]);
        m = fmaxf(m, __shfl_xor(m, 1, 64));
        m = fmaxf(m, __shfl_xor(m, 2, 64));
        m = fmaxf(m, __shfl_xor(m, 4, 64));
        float sum = 0.f;
        #pragma unroll
        for (int k = 0; k < 8; ++k) { v[k] = expf(v[k] - m); sum += v[k]; }
        sum += __shfl_xor(sum, 1, 64);
        sum += __shfl_xor(sum, 2, 64);
        sum += __shfl_xor(sum, 4, 64);
        const float inv = 1.f / sum;
        #pragma unroll
        for (int k = 0; k < 8; ++k) {
          const int q = j * 8 + k;
          const float p = v[k] * inv;
          pqS[grp][q] = p; pqT[q][grp] = p;
        }
      }
    }
    if (t >= 128 && t < 192) {           // window column softmax
      const int q = t - 128;
      float m = -3.0e38f;
      for (int r = 0; r < NW; ++r) if (r < cntS) m = fmaxf(m, sA[r][q]);
      float sum = 0.f;
      for (int r = 0; r < NW; ++r) {
        float e = 0.f;
        if (r < cntS) { e = expf(sA[r][q] - m); sum += e; }
        pcA[r][q] = e;
      }
      const float inv = (cntS > 0) ? 1.f / sum : 0.f;
      for (int r = 0; r < NW; ++r) pcA[r][q] *= inv;
    } else if (t >= 192) {               // gap column softmax
      const int q = t - 192;
      float m = -3.0e38f;
      for (int g = 0; g < GG; ++g) m = fmaxf(m, sA[NW + g][q]);
      float sum = 0.f;
      for (int g = 0; g < GG; ++g) {
        const float e = expf(sA[NW + g][q] - m);
        pcA[NW + g][q] = e; sum += e;
      }
      const float inv = 1.f / sum;
      for (int g = 0; g < GG; ++g) pcA[NW + g][q] *= inv;
    }
  }
  __syncthreads();

  // ---------------- M = pq·pc^T (8-lane groups) ----------------------------
  {
    const int g32 = t >> 3, j = t & 7;
    for (int e = g32; e < 637; e += 32) {
      const float *pr, *pc;
      int r2c, rdst = 0;
      if (e < 625) {
        const int r = e / 25; r2c = e - 25 * r; rdst = r;
        pr = &pqS[r][0]; pc = &pcA[r2c][0];
      } else {
        r2c = e - 625;
        pr = &pqS[NW][0]; pc = &pcA[NW + r2c][0];
      }
      const float4* pr4 = (const float4*)(pr + j * 8);
      const float4* pc4 = (const float4*)(pc + j * 8);
      const float4 a0 = pr4[0], a1 = pr4[1], b0 = pc4[0], b1 = pc4[1];
      float s = a0.x*b0.x + a0.y*b0.y + a0.z*b0.z + a0.w*b0.w
              + a1.x*b1.x + a1.y*b1.y + a1.z*b1.z + a1.w*b1.w;
      s += __shfl_xor(s, 1, 64);
      s += __shfl_xor(s, 2, 64);
      s += __shfl_xor(s, 4, 64);
      if (j == 0) { if (e < 625) MTS[r2c][rdst] = s; else MgS[r2c] = s; }
    }
  }
  __syncthreads();

  // ---------------- a-pass + per-d epilogue (t<200), att part (all) --------
  float acc = 0.f;
  if (t < DD) {
    const int d = t;
    float aacc[27];
    #pragma unroll
    for (int r = 0; r < 27; ++r) aacc[r] = 0.f;
    #pragma unroll 2
    for (int q = 0; q < QQ; ++q) {
      const float vq = qeS[IDX_QE(q, 0) + d];
      const float4* pr = (const float4*)&pqT[q][0];
      DOT27(aacc, pr, vq);
    }

    const float* wm  = x ? wM  : wMs;
    const float* wa2 = x ? wA2 : wA2s;

    // gap features for g = x
    const float cg = cA[NW + x][d];
    const float aG = aacc[25];
    float b2G = 0.f;
    #pragma unroll
    for (int g = 0; g < GG; ++g) b2G += MgS[g] * cA[NW + g][d];
    acc += cg * (wa2[d] + wm[d]) + aG * wa2[DD + d]
         + cg * aG * wa2[2 * DD + d] + cg * b2G * wa2[3 * DD + d];

    if (x == 0) {
      const float inv0 = 1.f / cnt0S;
      float mx = -3.0e38f, sm = 0.f;
      #pragma unroll
      for (int c = 0; c < 16; ++c) {
        mx = fmaxf(mx, ws[OFF_PMM + (size_t)(b * 16 + c) * DD + d]);
        sm += ws[OFF_PMS + (size_t)(b * 16 + c) * DD + d];
      }
      acc += mx * wm[DD + d] + sm * inv0 * wm[2 * DD + d];
    } else {
      float b2acc[25];
      #pragma unroll
      for (int r = 0; r < NW; ++r) b2acc[r] = 0.f;
      #pragma unroll 5
      for (int r2 = 0; r2 < NW; ++r2) {
        const float cv = cA[r2][d];
        const float4* mr = (const float4*)&MTS[r2][0];
        DOT25(b2acc, mr, cv);
      }
      const int cnt = cntS;
      const float invc = 1.f / (float)cnt;
      const float ac = aacc[26];
      float maxc = 0.f, sumc = 0.f, maxa = ac, suma = 0.f;
      float maxca = 0.f, sumca = 0.f, maxcb = 0.f, sumcb = 0.f;
      #pragma unroll
      for (int r = 0; r < NW; ++r) {
        if (r < cnt) {
          const float c = cA[r][d], a = aacc[r];
          maxc = fmaxf(maxc, c); sumc += c;
          maxa = fmaxf(maxa, a); suma += a;
          const float ca = c * a; maxca = fmaxf(maxca, ca); sumca += ca;
          const float cb = c * b2acc[r]; maxcb = fmaxf(maxcb, cb); sumcb += cb;
        }
      }
      suma += (float)(LL - cnt) * ac;
      acc += maxc * (wm[DD + d] + wa2[AD + d]) + sumc * invc * (wm[2 * DD + d] + wa2[2 * AD + d]);
      acc += maxa * wa2[AD + DD + d]      + suma  * invc * wa2[2 * AD + DD + d];
      acc += maxca * wa2[AD + 2 * DD + d] + sumca * invc * wa2[2 * AD + 2 * DD + d];
      acc += maxcb * wa2[AD + 3 * DD + d] + sumcb * invc * wa2[2 * AD + 3 * DD + d];
    }
  }

  {
    const float* wa = x ? wA : wAs;
    const float* arow = att + ((size_t)b * LL + gidS) * AD;
    if (x == 0) {
      const float inv0 = 1.f / cnt0S;
      for (int f = t; f < AD; f += 256) {
        float mx = -3.0e38f, sm = 0.f;
        #pragma unroll
        for (int c = 0; c < 16; ++c) {
          mx = fmaxf(mx, ws[OFF_PAM + (size_t)(b * 16 + c) * AD + f]);
          sm += ws[OFF_PAS + (size_t)(b * 16 + c) * AD + f];
        }
        acc += mx * wa[AD + f] + sm * inv0 * wa[2 * AD + f] + arow[f] * wa[f];
      }
    } else {
      const int cnt = cntS;
      const float invc = 1.f / (float)cnt;
      for (int f = t; f < AD; f += 256) {
        float mx = 0.f, sm = 0.f;
        #pragma unroll
        for (int r = 0; r < NW; ++r) {
          if (r < cnt) {
            const float v = att[((size_t)b * LL + rowsS[r]) * AD + f];
            mx = fmaxf(mx, v); sm += v;
          }
        }
        acc += mx * wa[AD + f] + sm * invc * wa[2 * AD + f] + arow[f] * wa[f];
      }
    }
  }

  const float tot = block_sum256(acc, red);
  if (t == 0) {
    const float bsum = x ? (bA[0] + bM[0] + bA2[0]) : (bAs[0] + bMs[0] + bA2s[0]);
    out[b * GG + x] = tot + bsum;
  }
}

// ============================================================================
extern "C" void kernel_launch(void* const* d_in, const int* in_sizes, int n_in,
                              void* d_out, int out_size, void* d_ws, size_t ws_size,
                              hipStream_t stream) {
  (void)in_sizes; (void)n_in; (void)out_size; (void)ws_size;
  const float* att    = (const float*)d_in[0];
  const float* mod    = (const float*)d_in[1];
  const int*   gaps   = (const int*)  d_in[2];
  const int*   mask   = (const int*)  d_in[3];
  const float* q_enc  = (const float*)d_in[4];
  const int*   q_mask = (const int*)  d_in[5];
  const float* cwv    = (const float*)d_in[6];
  const float* qwv    = (const float*)d_in[7];
  const float* cqw    = (const float*)d_in[8];
  const float* biasp  = (const float*)d_in[9];
  const float* wA     = (const float*)d_in[10];
  const float* bA     = (const float*)d_in[11];
  const float* wM     = (const float*)d_in[12];
  const float* bM     = (const float*)d_in[13];
  const float* wA2    = (const float*)d_in[14];
  const float* bA2    = (const float*)d_in[15];
  const float* wAs    = (const float*)d_in[16];
  const float* bAs    = (const float*)d_in[17];
  const float* wMs    = (const float*)d_in[18];
  const float* bMs    = (const float*)d_in[19];
  const float* wA2s   = (const float*)d_in[20];
  const float* bA2s   = (const float*)d_in[21];
  float* out = (float*)d_out;
  float* ws  = (float*)d_ws;

  hipLaunchKernelGGL(k_pool_att, dim3(16, 16), dim3(256), 0, stream, att, ws);
  hipLaunchKernelGGL(k_pool_mod, dim3(16, 16), dim3(64), 0, stream, mod, ws);
  hipLaunchKernelGGL(k_main, dim3(GG, 16), dim3(256), 0, stream,
                     att, mod, gaps, mask, q_enc, q_mask,
                     cwv, qwv, cqw, biasp,
                     wA, bA, wM, bM, wA2, bA2, wAs, bAs, wMs, bMs, wA2s, bA2s,
                     ws, out);
}

// Round 4
// 266.790 us; speedup vs baseline: 1.5110x; 1.1478x over previous
//
#include <hip/hip_runtime.h>
#include <math.h>

// ============================================================================
// GTOutputWithPooling2DoubleAttBig — MI355X (gfx950)  R3 (resubmit, infra fail)
//  * pools: 1024-thr blocks, unroll-4 float4 streaming, in-block merge (HBM-bound)
//  * k_main: 1024 thr (16 waves/CU); q_enc OFF LDS (qeT global coalesced);
//    4-slab a/b2/stat passes; pc softmax in-place over sA; x==0 partial -> ws
//  * k_finish: pool0 dots + biases for x==0 logits
// ============================================================================

constexpr int LL = 2048;
constexpr int GG = 12;
constexpr int QQ = 64;
constexpr int DD = 200;   // 2H
constexpr int AD = 800;   // 8H
constexpr int NW = 25;
constexpr float FNEG = -1e30f;

// ws layout (float offsets)
constexpr size_t OFF_QET  = 0;        // [16][50][64][4]  q_enc*cqw, transposed
constexpr size_t OFF_S1   = 204800;   // [16][64]
constexpr size_t OFF_PART = 205824;   // [16]  x==0 partial logits
constexpr size_t OFF_PAM  = 205840;   // [16][16][800] att pool0 max partials
constexpr size_t OFF_PAS  = 410640;   // att pool0 sum partials
constexpr size_t OFF_PMM  = 615440;   // [16][16][200] mod pool0 max partials
constexpr size_t OFF_PMS  = 666640;   // end = 717840 floats (2.87 MB)

__device__ __forceinline__ float dot4(const float4 a, const float4 b) {
  return a.x*b.x + a.y*b.y + a.z*b.z + a.w*b.w;
}
__device__ __forceinline__ float4 max4(const float4 a, const float4 b) {
  return make_float4(fmaxf(a.x,b.x), fmaxf(a.y,b.y), fmaxf(a.z,b.z), fmaxf(a.w,b.w));
}
__device__ __forceinline__ float4 add4(const float4 a, const float4 b) {
  return make_float4(a.x+b.x, a.y+b.y, a.z+b.z, a.w+b.w);
}
__device__ __forceinline__ float wave_sum(float v) {
  #pragma unroll
  for (int o = 32; o > 0; o >>= 1) v += __shfl_down(v, o, 64);
  return v;
}

// ============================================================================
// k_pre: qeT[b][j][q][4] = q_enc*cqw (transposed for coalesced s2 reads);
//        s1[b][q] = q_enc[q]·qw.   grid (4,16) x 256
// ============================================================================
__global__ __launch_bounds__(256) void k_pre(const float* __restrict__ q_enc,
                                             const float* __restrict__ qwv,
                                             const float* __restrict__ cqw,
                                             float* __restrict__ ws) {
  const int qs = blockIdx.x, b = blockIdx.y, t = threadIdx.x;
  const int ql = t >> 4, jt = t & 15;
  const int q = qs * 16 + ql;
  float s1 = 0.f;
  #pragma unroll
  for (int k = 0; k < 4; ++k) {
    const int j = jt + 16 * k;
    if (j < 50) {
      const float4 v  = ((const float4*)(q_enc + ((size_t)b * QQ + q) * DD))[j];
      const float4 cw = ((const float4*)cqw)[j];
      const float4 qw = ((const float4*)qwv)[j];
      float4 o; o.x = v.x*cw.x; o.y = v.y*cw.y; o.z = v.z*cw.z; o.w = v.w*cw.w;
      ((float4*)(ws + OFF_QET + (size_t)b * 12800))[j * 64 + q] = o;
      s1 += dot4(v, qw);
    }
  }
  s1 += __shfl_xor(s1, 1, 64);
  s1 += __shfl_xor(s1, 2, 64);
  s1 += __shfl_xor(s1, 4, 64);
  s1 += __shfl_xor(s1, 8, 64);
  if (jt == 0) ws[OFF_S1 + b * QQ + q] = s1;
}

// ============================================================================
// k_pool_att: grid (16,16) x 1024. chunk=128 rows, 4 quarters x 32 rows.
// ============================================================================
__global__ __launch_bounds__(1024) void k_pool_att(const float* __restrict__ att,
                                                   float* __restrict__ ws) {
  const int ch = blockIdx.x, b = blockIdx.y, t = threadIdx.x;
  __shared__ __align__(16) float stA[4][200][8];
  if (t < 800) {
    const int qt = t / 200, col = t - qt * 200;
    const float4* p = (const float4*)(att + ((size_t)b * LL + ch * 128 + qt * 32) * AD) + col;
    float4 m = make_float4(-3e38f, -3e38f, -3e38f, -3e38f);
    float4 s = make_float4(0.f, 0.f, 0.f, 0.f);
    for (int i = 0; i < 32; i += 4) {
      const float4 v0 = p[(size_t)(i + 0) * 200];
      const float4 v1 = p[(size_t)(i + 1) * 200];
      const float4 v2 = p[(size_t)(i + 2) * 200];
      const float4 v3 = p[(size_t)(i + 3) * 200];
      m = max4(m, max4(max4(v0, v1), max4(v2, v3)));
      s = add4(s, add4(add4(v0, v1), add4(v2, v3)));
    }
    *(float4*)&stA[qt][col][0] = m;
    *(float4*)&stA[qt][col][4] = s;
  }
  __syncthreads();
  if (t < 200) {
    float4 m = *(const float4*)&stA[0][t][0];
    float4 s = *(const float4*)&stA[0][t][4];
    #pragma unroll
    for (int qt = 1; qt < 4; ++qt) {
      m = max4(m, *(const float4*)&stA[qt][t][0]);
      s = add4(s, *(const float4*)&stA[qt][t][4]);
    }
    ((float4*)(ws + OFF_PAM))[(size_t)(b * 16 + ch) * 200 + t] = m;
    ((float4*)(ws + OFF_PAS))[(size_t)(b * 16 + ch) * 200 + t] = s;
  }
}

// ============================================================================
// k_pool_mod: grid (16,16) x 512. chunk=128 rows, 8 groups x 16 rows.
// ============================================================================
__global__ __launch_bounds__(512) void k_pool_mod(const float* __restrict__ mod,
                                                  float* __restrict__ ws) {
  const int ch = blockIdx.x, b = blockIdx.y, t = threadIdx.x;
  __shared__ __align__(16) float stM[8][50][8];
  if (t < 400) {
    const int rg = t / 50, col = t - rg * 50;
    const float4* p = (const float4*)(mod + ((size_t)b * LL + ch * 128 + rg * 16) * DD) + col;
    float4 m = make_float4(-3e38f, -3e38f, -3e38f, -3e38f);
    float4 s = make_float4(0.f, 0.f, 0.f, 0.f);
    for (int i = 0; i < 16; i += 4) {
      const float4 v0 = p[(size_t)(i + 0) * 50];
      const float4 v1 = p[(size_t)(i + 1) * 50];
      const float4 v2 = p[(size_t)(i + 2) * 50];
      const float4 v3 = p[(size_t)(i + 3) * 50];
      m = max4(m, max4(max4(v0, v1), max4(v2, v3)));
      s = add4(s, add4(add4(v0, v1), add4(v2, v3)));
    }
    *(float4*)&stM[rg][col][0] = m;
    *(float4*)&stM[rg][col][4] = s;
  }
  __syncthreads();
  if (t < 50) {
    float4 m = *(const float4*)&stM[0][t][0];
    float4 s = *(const float4*)&stM[0][t][4];
    #pragma unroll
    for (int rg = 1; rg < 8; ++rg) {
      m = max4(m, *(const float4*)&stM[rg][t][0]);
      s = add4(s, *(const float4*)&stM[rg][t][4]);
    }
    ((float4*)(ws + OFF_PMM))[(size_t)(b * 16 + ch) * 50 + t] = m;
    ((float4*)(ws + OFF_PMS))[(size_t)(b * 16 + ch) * 50 + t] = s;
  }
}

// ============================================================================
// k_main: per (b,x) full bidaf + window pools + logit. grid (12,16) x 1024.
// ============================================================================
__global__ __launch_bounds__(1024, 4) void k_main(
    const float* __restrict__ att, const float* __restrict__ mod,
    const int* __restrict__ gaps, const int* __restrict__ mask,
    const float* __restrict__ q_enc, const int* __restrict__ q_mask,
    const float* __restrict__ cwv,
    const float* __restrict__ wA,  const float* __restrict__ bA,
    const float* __restrict__ wM,  const float* __restrict__ bM,
    const float* __restrict__ wA2, const float* __restrict__ bA2,
    const float* __restrict__ wAs, const float* __restrict__ wMs,
    const float* __restrict__ wA2s,
    float* __restrict__ ws, float* __restrict__ out) {

  const int x = blockIdx.x, b = blockIdx.y, t = threadIdx.x;
  const int w = t >> 6, lane = t & 63;

  __shared__ __align__(16) float cA[37][200];
  __shared__ __align__(16) float sA[37][68];   // scores -> pc (in-place)
  __shared__ __align__(16) float pqS[27][68];
  __shared__ __align__(16) float pqT[64][28];
  __shared__ __align__(16) float MTS[25][28];  // MTS[r2][r] = M[r][r2]
  __shared__ float MgS[12];
  __shared__ float statS[4][2600];             // per-slab stats, stride 13
  __shared__ float s0A[37];
  __shared__ float s1S[64];
  __shared__ float red[16];
  __shared__ int rowsS[37];
  __shared__ int qmS[64];
  __shared__ int cntS, gidS;

  // ---------------- P0: qmask + window-row compaction ----------------
  if (t >= 64 && t < 80) ((int4*)qmS)[t - 64] = ((const int4*)(q_mask + b * QQ))[t - 64];
  if (w == 15) {
    const int gid = gaps[b * GG + x];
    if (lane == 0) gidS = gid;
    if (lane >= 32 && lane < 44) rowsS[NW + lane - 32] = gaps[b * GG + (lane - 32)];
    bool ok = false; int pos = 0;
    if (x > 0 && lane < NW) {
      const int lo = max(gid - 12, 0), hi = min(gid + 12, LL - 1);
      pos = lo + lane;
      ok = (pos <= hi) && (mask[(size_t)b * LL + pos] > 0);
    }
    const unsigned long long bal = __ballot(ok);
    if (lane < NW) rowsS[lane] = gid;                    // default (valid row)
    if (ok) rowsS[__popcll(bal & ((1ull << lane) - 1ull))] = pos;
    if (lane == 0) cntS = (x > 0) ? (int)__popcll(bal) : 0;
  }
  __syncthreads();

  // ---------------- P1: stage cA rows + s1S ----------------
  for (int i = t; i < 37 * 50; i += 1024) {
    const int rr = i / 50, dc = (i - rr * 50) * 4;
    *(float4*)&cA[rr][dc] = *(const float4*)(mod + ((size_t)b * LL + rowsS[rr]) * DD + dc);
  }
  if (t >= 896 && t < 960) s1S[t - 896] = ws[OFF_S1 + b * QQ + (t - 896)];
  __syncthreads();

  // ---------------- P2: s0 (t<37) + s2 scores (all waves) ----------------
  if (t < 37) {
    float a = 0.f;
    for (int k = 0; k < 50; ++k)
      a += dot4(*(const float4*)&cA[t][k * 4], ((const float4*)cwv)[k]);
    s0A[t] = a;
  }
  {
    const int rBase = (x == 0) ? NW : 0;
    const int nR = (x == 0) ? GG : 37;
    const float* qet = ws + OFF_QET + (size_t)b * 12800;
    const int r0 = w, r1 = w + 16, r2r = w + 32;
    const bool h0 = r0 < nR, h1 = r1 < nR, h2 = r2r < nR;
    const int rr0 = rBase + (h0 ? r0 : 0);
    const int rr1 = rBase + (h1 ? r1 : 0);
    const int rr2 = rBase + (h2 ? r2r : 0);
    float a0 = 0.f, a1 = 0.f, a2 = 0.f;
    for (int j = 0; j < 50; ++j) {
      const float4 qv = ((const float4*)qet)[j * 64 + lane];
      a0 += dot4(*(const float4*)&cA[rr0][j * 4], qv);
      a1 += dot4(*(const float4*)&cA[rr1][j * 4], qv);
      a2 += dot4(*(const float4*)&cA[rr2][j * 4], qv);
    }
    if (h0) sA[rr0][lane] = a0;
    if (h1) sA[rr1][lane] = a1;
    if (h2) sA[rr2][lane] = a2;
  }
  __syncthreads();

  // ---------------- P3: softmaxes into registers ----------------
  // row softmax (pq): s2 + s1[q] (s0,bias cancel). col softmax: s2 + s0[r].
  float pv[8];
  const bool rowAct = (t < 216);
  const int grp = t >> 3, j8 = t & 7;
  if (rowAct) {
    if (grp < NW && grp >= cntS) {
      #pragma unroll
      for (int k = 0; k < 8; ++k) pv[k] = 0.f;
    } else {
      const int srow = (grp < NW) ? grp : (NW + x);
      #pragma unroll
      for (int k = 0; k < 8; ++k) {
        const int q = j8 * 8 + k;
        const float s = (grp == 26) ? s1S[q] : (sA[srow][q] + s1S[q]);
        pv[k] = (qmS[q] > 0) ? s : FNEG;
      }
      float m = pv[0];
      #pragma unroll
      for (int k = 1; k < 8; ++k) m = fmaxf(m, pv[k]);
      m = fmaxf(m, __shfl_xor(m, 1, 64));
      m = fmaxf(m, __shfl_xor(m, 2, 64));
      m = fmaxf(m, __shfl_xor(m, 4, 64));
      float sum = 0.f;
      #pragma unroll
      for (int k = 0; k < 8; ++k) { pv[k] = expf(pv[k] - m); sum += pv[k]; }
      sum += __shfl_xor(sum, 1, 64);
      sum += __shfl_xor(sum, 2, 64);
      sum += __shfl_xor(sum, 4, 64);
      const float inv = 1.f / sum;
      #pragma unroll
      for (int k = 0; k < 8; ++k) pv[k] *= inv;
    }
  }
  float pcv[37];
  const bool colAct = (t >= 256 && t < 320);
  if (colAct) {
    const int qc = t - 256;
    const int cnt = cntS;
    float mW = -3e38f;
    for (int r = 0; r < NW; ++r)
      if (r < cnt) mW = fmaxf(mW, sA[r][qc] + s0A[r]);
    float sum = 0.f;
    for (int r = 0; r < NW; ++r) {
      float e = 0.f;
      if (r < cnt) { e = expf(sA[r][qc] + s0A[r] - mW); sum += e; }
      pcv[r] = e;
    }
    const float inv = (cnt > 0) ? (1.f / sum) : 0.f;
    for (int r = 0; r < NW; ++r) pcv[r] *= inv;
    float mG = -3e38f;
    for (int g = 0; g < GG; ++g) mG = fmaxf(mG, sA[NW + g][qc] + s0A[NW + g]);
    sum = 0.f;
    for (int g = 0; g < GG; ++g) {
      const float e = expf(sA[NW + g][qc] + s0A[NW + g] - mG);
      pcv[NW + g] = e; sum += e;
    }
    const float invg = 1.f / sum;
    for (int g = 0; g < GG; ++g) pcv[NW + g] *= invg;
  }
  __syncthreads();

  // ---------------- P4: write pq (pqS+pqT) and pc (over sA) ----------------
  if (rowAct) {
    *(float4*)&pqS[grp][j8 * 8]     = make_float4(pv[0], pv[1], pv[2], pv[3]);
    *(float4*)&pqS[grp][j8 * 8 + 4] = make_float4(pv[4], pv[5], pv[6], pv[7]);
    #pragma unroll
    for (int k = 0; k < 8; ++k) pqT[j8 * 8 + k][grp] = pv[k];
  }
  if (colAct) {
    const int qc = t - 256;
    for (int r = 0; r < 37; ++r) sA[r][qc] = pcv[r];
  }
  if (t >= 320 && t < 384) pqT[t - 320][27] = 0.f;
  __syncthreads();

  // ---------------- P5: M = pq·pc^T (thread per entry) ----------------
  if (t < 637) {
    int pr, pc;
    if (t < 625) { pr = t / 25; pc = t - pr * 25; }
    else         { pr = 25;     pc = NW + (t - 625); }
    float s = 0.f;
    #pragma unroll 4
    for (int k4 = 0; k4 < 16; ++k4)
      s += dot4(*(const float4*)&pqS[pr][k4 * 4], *(const float4*)&sA[pc][k4 * 4]);
    if (t < 625) MTS[pc][pr] = s; else MgS[t - 625] = s;
  }
  if (t >= 640 && t < 715) { const int e = t - 640; MTS[e / 3][25 + e % 3] = 0.f; }
  __syncthreads();

  // ---------------- P6: slab a-pass + b2 + window stats ----------------
  {
    const int slab = t >> 8, d = t & 255;
    if (d < 200) {
      const int r0 = 8 * slab;                       // slab3 -> 24
      float a[8] = {0,0,0,0,0,0,0,0};
      float bb[8] = {0,0,0,0,0,0,0,0};
      const float* qe = q_enc + (size_t)b * QQ * DD + d;
      if (slab < 3) {
        #pragma unroll 4
        for (int q = 0; q < QQ; ++q) {
          const float vq = qe[(size_t)q * DD];
          const float4 p0 = *(const float4*)&pqT[q][r0];
          const float4 p1 = *(const float4*)&pqT[q][r0 + 4];
          a[0] += p0.x*vq; a[1] += p0.y*vq; a[2] += p0.z*vq; a[3] += p0.w*vq;
          a[4] += p1.x*vq; a[5] += p1.y*vq; a[6] += p1.z*vq; a[7] += p1.w*vq;
        }
        #pragma unroll 5
        for (int r2 = 0; r2 < NW; ++r2) {
          const float cv = cA[r2][d];
          const float4 m0 = *(const float4*)&MTS[r2][r0];
          const float4 m1 = *(const float4*)&MTS[r2][r0 + 4];
          bb[0] += m0.x*cv; bb[1] += m0.y*cv; bb[2] += m0.z*cv; bb[3] += m0.w*cv;
          bb[4] += m1.x*cv; bb[5] += m1.y*cv; bb[6] += m1.z*cv; bb[7] += m1.w*cv;
        }
      } else {
        #pragma unroll 4
        for (int q = 0; q < QQ; ++q) {
          const float vq = qe[(size_t)q * DD];
          const float4 p0 = *(const float4*)&pqT[q][24];
          a[0] += p0.x*vq; a[1] += p0.y*vq; a[2] += p0.z*vq; a[3] += p0.w*vq;
        }
        #pragma unroll 5
        for (int r2 = 0; r2 < NW; ++r2) {
          const float cv = cA[r2][d];
          const float4 m0 = *(const float4*)&MTS[r2][24];
          bb[0] += m0.x*cv;
        }
      }
      const int cnt = cntS;
      float mxa = -3e38f, sma = 0.f, mxca = -3e38f, smca = 0.f;
      float mxcb = -3e38f, smcb = 0.f, aG = 0.f;
      if (slab < 3) {
        #pragma unroll
        for (int k = 0; k < 8; ++k) {
          const int r = r0 + k;
          if (r < cnt) {
            const float av = a[k], cv = cA[r][d];
            mxa = fmaxf(mxa, av); sma += av;
            const float ca = cv * av; mxca = fmaxf(mxca, ca); smca += ca;
            const float cb = cv * bb[k]; mxcb = fmaxf(mxcb, cb); smcb += cb;
          }
        }
      } else {
        if (24 < cnt) {
          const float av = a[0], cv = cA[24][d];
          mxa = fmaxf(mxa, av); sma += av;
          const float ca = cv * av; mxca = fmaxf(mxca, ca); smca += ca;
          const float cb = cv * bb[0]; mxcb = fmaxf(mxcb, cb); smcb += cb;
        }
        aG = a[1];
        const float ac = a[2];
        mxa = fmaxf(mxa, ac);
        sma += (float)(LL - cnt) * ac;
      }
      float* sp = &statS[slab][d * 13];
      sp[0] = mxa; sp[1] = sma; sp[2] = mxca; sp[3] = smca;
      sp[4] = mxcb; sp[5] = smcb; sp[6] = aG;
    }
  }
  __syncthreads();

  // ---------------- P7: merge stats + gap features + att part ----------------
  float acc = 0.f;
  const float* wa  = x ? wA  : wAs;
  const float* wm  = x ? wM  : wMs;
  const float* wa2 = x ? wA2 : wA2s;
  if (t < 200) {
    const int d = t;
    float mxa = -3e38f, sma = 0.f, mxca = 0.f, smca = 0.f, mxcb = 0.f, smcb = 0.f;
    #pragma unroll
    for (int s = 0; s < 4; ++s) {
      const float* sp = &statS[s][d * 13];
      mxa = fmaxf(mxa, sp[0]); sma += sp[1];
      mxca = fmaxf(mxca, sp[2]); smca += sp[3];
      mxcb = fmaxf(mxcb, sp[4]); smcb += sp[5];
    }
    const float aG = statS[3][d * 13 + 6];
    const float cg = cA[NW + x][d];
    float b2G = 0.f;
    #pragma unroll
    for (int g = 0; g < GG; ++g) b2G += MgS[g] * cA[NW + g][d];
    acc += cg * (wa2[d] + wm[d]) + aG * wa2[DD + d]
         + cg * aG * wa2[2 * DD + d] + cg * b2G * wa2[3 * DD + d];
    if (x > 0) {
      const int cnt = cntS;
      const float invc = 1.f / (float)cnt;
      float mxc = 0.f, smc = 0.f;
      #pragma unroll
      for (int r = 0; r < NW; ++r) {
        if (r < cnt) { const float cv = cA[r][d]; mxc = fmaxf(mxc, cv); smc += cv; }
      }
      acc += mxc * (wm[DD + d] + wa2[AD + d]) + smc * invc * (wm[2 * DD + d] + wa2[2 * AD + d]);
      acc += mxa * wa2[AD + DD + d]       + sma  * invc * wa2[2 * AD + DD + d];
      acc += mxca * wa2[AD + 2 * DD + d]  + smca * invc * wa2[2 * AD + 2 * DD + d];
      acc += mxcb * wa2[AD + 3 * DD + d]  + smcb * invc * wa2[2 * AD + 3 * DD + d];
    }
    // att: gap-row dot (+ window pool for x>0), float4 column t
    const float4 w0 = ((const float4*)wa)[t];
    const float4 ar = ((const float4*)(att + ((size_t)b * LL + gidS) * AD))[t];
    acc += dot4(ar, w0);
    if (x > 0) {
      const float4 w1 = ((const float4*)(wa + AD))[t];
      const float4 w2 = ((const float4*)(wa + 2 * AD))[t];
      float4 mx = make_float4(0.f, 0.f, 0.f, 0.f);
      float4 sm = make_float4(0.f, 0.f, 0.f, 0.f);
      const int cnt = cntS;
      for (int r = 0; r < NW; ++r) {
        if (r < cnt) {
          const float4 v = ((const float4*)(att + ((size_t)b * LL + rowsS[r]) * AD))[t];
          mx = max4(mx, v); sm = add4(sm, v);
        }
      }
      const float invc = 1.f / (float)cnt;
      acc += dot4(mx, w1) + invc * dot4(sm, w2);
    }
  }
  // block reduce (1024 threads)
  const float wsum = wave_sum(acc);
  if (lane == 0) red[w] = wsum;
  __syncthreads();
  if (t == 0) {
    float s = 0.f;
    #pragma unroll
    for (int i = 0; i < 16; ++i) s += red[i];
    if (x == 0) ws[OFF_PART + b] = s;
    else out[b * GG + x] = s + bA[0] + bM[0] + bA2[0];
  }
}

// ============================================================================
// k_finish: pool0 dots + partial + biases -> out[b][0]. grid 16 x 256.
// ============================================================================
__global__ __launch_bounds__(256) void k_finish(const int* __restrict__ mask,
    const float* __restrict__ wAs, const float* __restrict__ bAs,
    const float* __restrict__ wMs, const float* __restrict__ bMs,
    const float* __restrict__ bA2s,
    const float* __restrict__ ws, float* __restrict__ out) {
  const int b = blockIdx.x, t = threadIdx.x;
  __shared__ float red[4];
  __shared__ float inv0S;
  int cm = 0;
  for (int l = t; l < LL; l += 256) cm += (mask[(size_t)b * LL + l] > 0) ? 1 : 0;
  const float cf = wave_sum((float)cm);
  if ((t & 63) == 0) red[t >> 6] = cf;
  __syncthreads();
  if (t == 0) inv0S = 1.f / (red[0] + red[1] + red[2] + red[3]);
  __syncthreads();
  const float inv0 = inv0S;
  float acc = 0.f;
  if (t < 200) {
    float4 m = ((const float4*)(ws + OFF_PAM))[(size_t)(b * 16) * 200 + t];
    float4 s = ((const float4*)(ws + OFF_PAS))[(size_t)(b * 16) * 200 + t];
    for (int ch = 1; ch < 16; ++ch) {
      m = max4(m, ((const float4*)(ws + OFF_PAM))[(size_t)(b * 16 + ch) * 200 + t]);
      s = add4(s, ((const float4*)(ws + OFF_PAS))[(size_t)(b * 16 + ch) * 200 + t]);
    }
    acc += dot4(m, ((const float4*)(wAs + AD))[t]) + inv0 * dot4(s, ((const float4*)(wAs + 2 * AD))[t]);
  }
  if (t < 50) {
    float4 m = ((const float4*)(ws + OFF_PMM))[(size_t)(b * 16) * 50 + t];
    float4 s = ((const float4*)(ws + OFF_PMS))[(size_t)(b * 16) * 50 + t];
    for (int ch = 1; ch < 16; ++ch) {
      m = max4(m, ((const float4*)(ws + OFF_PMM))[(size_t)(b * 16 + ch) * 50 + t]);
      s = add4(s, ((const float4*)(ws + OFF_PMS))[(size_t)(b * 16 + ch) * 50 + t]);
    }
    acc += dot4(m, ((const float4*)(wMs + DD))[t]) + inv0 * dot4(s, ((const float4*)(wMs + 2 * DD))[t]);
  }
  __syncthreads();
  const float tot = wave_sum(acc);
  if ((t & 63) == 0) red[t >> 6] = tot;
  __syncthreads();
  if (t == 0)
    out[b * GG] = red[0] + red[1] + red[2] + red[3] + ws[OFF_PART + b]
                + bAs[0] + bMs[0] + bA2s[0];
}

// ============================================================================
extern "C" void kernel_launch(void* const* d_in, const int* in_sizes, int n_in,
                              void* d_out, int out_size, void* d_ws, size_t ws_size,
                              hipStream_t stream) {
  (void)in_sizes; (void)n_in; (void)out_size; (void)ws_size;
  const float* att    = (const float*)d_in[0];
  const float* mod    = (const float*)d_in[1];
  const int*   gaps   = (const int*)  d_in[2];
  const int*   mask   = (const int*)  d_in[3];
  const float* q_enc  = (const float*)d_in[4];
  const int*   q_mask = (const int*)  d_in[5];
  const float* cwv    = (const float*)d_in[6];
  const float* qwv    = (const float*)d_in[7];
  const float* cqw    = (const float*)d_in[8];
  const float* wA     = (const float*)d_in[10];
  const float* bA     = (const float*)d_in[11];
  const float* wM     = (const float*)d_in[12];
  const float* bM     = (const float*)d_in[13];
  const float* wA2    = (const float*)d_in[14];
  const float* bA2    = (const float*)d_in[15];
  const float* wAs    = (const float*)d_in[16];
  const float* bAs    = (const float*)d_in[17];
  const float* wMs    = (const float*)d_in[18];
  const float* bMs    = (const float*)d_in[19];
  const float* wA2s   = (const float*)d_in[20];
  const float* bA2s   = (const float*)d_in[21];
  float* out = (float*)d_out;
  float* ws  = (float*)d_ws;

  hipLaunchKernelGGL(k_pre, dim3(4, 16), dim3(256), 0, stream, q_enc, qwv, cqw, ws);
  hipLaunchKernelGGL(k_main, dim3(GG, 16), dim3(1024), 0, stream,
                     att, mod, gaps, mask, q_enc, q_mask, cwv,
                     wA, bA, wM, bM, wA2, bA2, wAs, wMs, wA2s, ws, out);
  hipLaunchKernelGGL(k_pool_att, dim3(16, 16), dim3(1024), 0, stream, att, ws);
  hipLaunchKernelGGL(k_pool_mod, dim3(16, 16), dim3(512), 0, stream, mod, ws);
  hipLaunchKernelGGL(k_finish, dim3(16), dim3(256), 0, stream,
                     mask, wAs, bAs, wMs, bMs, bA2s, ws, out);
}

// Round 5
// 249.460 us; speedup vs baseline: 1.6160x; 1.0695x over previous
//
#include <hip/hip_runtime.h>
#include <math.h>

// ============================================================================
// GTOutputWithPooling2DoubleAttBig — MI355X (gfx950)  R5
// Unified role-split kernel: bidaf (192 blocks) + att-pool (512) + mod-pool (64)
// in ONE 512-thread kernel -> pools overlap bidaf, all CUs busy, 2 blocks/CU.
// k_pre (qeT, s1) -> k_uni -> k_finish (pool0 dots + x==0 logit).
// ============================================================================

constexpr int LL = 2048;
constexpr int GG = 12;
constexpr int QQ = 64;
constexpr int DD = 200;   // 2H
constexpr int AD = 800;   // 8H
constexpr int NW = 25;
constexpr float FNEG = -1e30f;

// ws layout (float offsets)
constexpr size_t OFF_QET  = 0;                       // [16][50][64][4]
constexpr size_t OFF_S1   = 204800;                  // [16][64]
constexpr size_t OFF_PART = 205824;                  // [16]
constexpr size_t OFF_PAM  = 205840;                  // [16][32][800]
constexpr size_t OFF_PAS  = OFF_PAM + 16 * 32 * 800; // 615440
constexpr size_t OFF_PMM  = OFF_PAS + 16 * 32 * 800; // 1025040 [16][4][200]
constexpr size_t OFF_PMS  = OFF_PMM + 16 * 4 * 200;  // 1037840

__device__ __forceinline__ float dot4(const float4 a, const float4 b) {
  return a.x*b.x + a.y*b.y + a.z*b.z + a.w*b.w;
}
__device__ __forceinline__ float4 max4(const float4 a, const float4 b) {
  return make_float4(fmaxf(a.x,b.x), fmaxf(a.y,b.y), fmaxf(a.z,b.z), fmaxf(a.w,b.w));
}
__device__ __forceinline__ float4 add4(const float4 a, const float4 b) {
  return make_float4(a.x+b.x, a.y+b.y, a.z+b.z, a.w+b.w);
}
__device__ __forceinline__ float wave_sum(float v) {
  #pragma unroll
  for (int o = 32; o > 0; o >>= 1) v += __shfl_down(v, o, 64);
  return v;
}

struct BidafLDS {
  float cA[37][200];     // window rows 0..24, gap rows 25..36
  float sA[37][68];      // s2 scores -> pc (in place)
  float pqS[27][68];
  float pqT[64][28];     // col 25 = gap-row-x, col 26 = const, col 27 = pad
  float MTS[25][28];     // MTS[r2][r] = M[r][r2], cols 25..27 = pad
  float statS[2][1408];  // per-slab stats, stride 7
  float MgS[12];
  float s0A[40];
  float s1S[64];
  float red[8];
  int   rowsS[40];
  int   qmS[64];
  int   cntS, gidS;
};
struct PoolLDS { float st[3208]; };

// ============================================================================
// k_pre: qeT[b][j][q][4] = q_enc*cqw (transposed); s1[b][q]. grid (4,16) x 256
// ============================================================================
__global__ __launch_bounds__(256) void k_pre(const float* __restrict__ q_enc,
                                             const float* __restrict__ qwv,
                                             const float* __restrict__ cqw,
                                             float* __restrict__ ws) {
  const int qs = blockIdx.x, b = blockIdx.y, t = threadIdx.x;
  const int ql = t >> 4, jt = t & 15;
  const int q = qs * 16 + ql;
  float s1 = 0.f;
  #pragma unroll
  for (int k = 0; k < 4; ++k) {
    const int j = jt + 16 * k;
    if (j < 50) {
      const float4 v  = ((const float4*)(q_enc + ((size_t)b * QQ + q) * DD))[j];
      const float4 cw = ((const float4*)cqw)[j];
      const float4 qw = ((const float4*)qwv)[j];
      float4 o; o.x = v.x*cw.x; o.y = v.y*cw.y; o.z = v.z*cw.z; o.w = v.w*cw.w;
      ((float4*)(ws + OFF_QET + (size_t)b * 12800))[j * 64 + q] = o;
      s1 += dot4(v, qw);
    }
  }
  s1 += __shfl_xor(s1, 1, 64);
  s1 += __shfl_xor(s1, 2, 64);
  s1 += __shfl_xor(s1, 4, 64);
  s1 += __shfl_xor(s1, 8, 64);
  if (jt == 0) ws[OFF_S1 + b * QQ + q] = s1;
}

// ============================================================================
// k_uni: grid 768 x 512.
//   bid <  192 : bidaf per (b,x)   b=bid/12, x=bid%12
//   bid <  704 : att pool, 64-row chunk   i=bid-192: b=i>>5, ch=i&31
//   else       : mod pool, 512-row chunk  i=bid-704: b=i>>2, q4=i&3
// ============================================================================
__global__ __launch_bounds__(512, 4) void k_uni(
    const float* __restrict__ att, const float* __restrict__ mod,
    const int* __restrict__ gaps, const int* __restrict__ mask,
    const float* __restrict__ q_enc, const int* __restrict__ q_mask,
    const float* __restrict__ cwv,
    const float* __restrict__ wA,  const float* __restrict__ bA,
    const float* __restrict__ wM,  const float* __restrict__ bM,
    const float* __restrict__ wA2, const float* __restrict__ bA2,
    const float* __restrict__ wAs, const float* __restrict__ wMs,
    const float* __restrict__ wA2s,
    float* __restrict__ ws, float* __restrict__ out) {

  __shared__ __align__(16) unsigned char LDSU[sizeof(BidafLDS)];
  const int bid = blockIdx.x, t = threadIdx.x;

  // ---------------------------------------------------------- pool roles ----
  if (bid >= 192) {
    PoolLDS& P = *reinterpret_cast<PoolLDS*>(LDSU);
    if (bid < 704) {
      // att pool: 64 rows, 2 half-groups x 32 rows, cols as float4
      const int i = bid - 192, b = i >> 5, ch = i & 31;
      if (t < 400) {
        const int qt = t / 200, col = t - qt * 200;
        const float4* p = (const float4*)(att + ((size_t)b * LL + ch * 64 + qt * 32) * AD) + col;
        float4 m = make_float4(-3e38f, -3e38f, -3e38f, -3e38f);
        float4 s = make_float4(0.f, 0.f, 0.f, 0.f);
        for (int r = 0; r < 32; r += 4) {
          const float4 v0 = p[(size_t)(r + 0) * 200];
          const float4 v1 = p[(size_t)(r + 1) * 200];
          const float4 v2 = p[(size_t)(r + 2) * 200];
          const float4 v3 = p[(size_t)(r + 3) * 200];
          m = max4(m, max4(max4(v0, v1), max4(v2, v3)));
          s = add4(s, add4(add4(v0, v1), add4(v2, v3)));
        }
        *(float4*)&P.st[(qt * 200 + col) * 8]     = m;
        *(float4*)&P.st[(qt * 200 + col) * 8 + 4] = s;
      }
      __syncthreads();
      if (t < 200) {
        float4 m = max4(*(const float4*)&P.st[t * 8],
                        *(const float4*)&P.st[(200 + t) * 8]);
        float4 s = add4(*(const float4*)&P.st[t * 8 + 4],
                        *(const float4*)&P.st[(200 + t) * 8 + 4]);
        ((float4*)(ws + OFF_PAM))[((size_t)b * 32 + ch) * 200 + t] = m;
        ((float4*)(ws + OFF_PAS))[((size_t)b * 32 + ch) * 200 + t] = s;
      }
    } else {
      // mod pool: 512 rows, 8 groups x 64 rows, cols as float4
      const int i = bid - 704, b = i >> 2, q4 = i & 3;
      if (t < 400) {
        const int rg = t / 50, col = t - rg * 50;
        const float4* p = (const float4*)(mod + ((size_t)b * LL + q4 * 512 + rg * 64) * DD) + col;
        float4 m = make_float4(-3e38f, -3e38f, -3e38f, -3e38f);
        float4 s = make_float4(0.f, 0.f, 0.f, 0.f);
        for (int r = 0; r < 64; r += 4) {
          const float4 v0 = p[(size_t)(r + 0) * 50];
          const float4 v1 = p[(size_t)(r + 1) * 50];
          const float4 v2 = p[(size_t)(r + 2) * 50];
          const float4 v3 = p[(size_t)(r + 3) * 50];
          m = max4(m, max4(max4(v0, v1), max4(v2, v3)));
          s = add4(s, add4(add4(v0, v1), add4(v2, v3)));
        }
        *(float4*)&P.st[(rg * 50 + col) * 8]     = m;
        *(float4*)&P.st[(rg * 50 + col) * 8 + 4] = s;
      }
      __syncthreads();
      if (t < 50) {
        float4 m = *(const float4*)&P.st[t * 8];
        float4 s = *(const float4*)&P.st[t * 8 + 4];
        #pragma unroll
        for (int rg = 1; rg < 8; ++rg) {
          m = max4(m, *(const float4*)&P.st[(rg * 50 + t) * 8]);
          s = add4(s, *(const float4*)&P.st[(rg * 50 + t) * 8 + 4]);
        }
        ((float4*)(ws + OFF_PMM))[((size_t)b * 4 + q4) * 50 + t] = m;
        ((float4*)(ws + OFF_PMS))[((size_t)b * 4 + q4) * 50 + t] = s;
      }
    }
    return;
  }

  // ---------------------------------------------------------- bidaf role ----
  BidafLDS& L = *reinterpret_cast<BidafLDS*>(LDSU);
  const int b = bid / 12, x = bid - 12 * (bid / 12);
  const int w = t >> 6, lane = t & 63;

  // P0: qmask + window-row compaction
  if (t >= 64 && t < 80) ((int4*)L.qmS)[t - 64] = ((const int4*)(q_mask + b * QQ))[t - 64];
  if (w == 7) {
    const int gid = gaps[b * GG + x];
    if (lane == 0) L.gidS = gid;
    if (lane >= 32 && lane < 44) L.rowsS[NW + lane - 32] = gaps[b * GG + (lane - 32)];
    bool ok = false; int pos = 0;
    if (x > 0 && lane < NW) {
      const int lo = max(gid - 12, 0), hi = min(gid + 12, LL - 1);
      pos = lo + lane;
      ok = (pos <= hi) && (mask[(size_t)b * LL + pos] > 0);
    }
    const unsigned long long bal = __ballot(ok);
    if (lane < NW) L.rowsS[lane] = gid;                 // default (valid row)
    if (ok) L.rowsS[__popcll(bal & ((1ull << lane) - 1ull))] = pos;
    if (lane == 0) L.cntS = (x > 0) ? (int)__popcll(bal) : 0;
  }
  __syncthreads();

  // P1: stage cA rows + s1S
  for (int i2 = t; i2 < 37 * 50; i2 += 512) {
    const int rr = i2 / 50, dc = (i2 - rr * 50) * 4;
    *(float4*)&L.cA[rr][dc] = *(const float4*)(mod + ((size_t)b * LL + L.rowsS[rr]) * DD + dc);
  }
  if (t >= 384 && t < 448) L.s1S[t - 384] = ws[OFF_S1 + b * QQ + (t - 384)];
  __syncthreads();

  // P2: s0 (t<37) + s2 scores (8 waves, lane=q, 5 rows/wave)
  if (t < 37) {
    float a = 0.f;
    for (int k = 0; k < 50; ++k)
      a += dot4(*(const float4*)&L.cA[t][k * 4], ((const float4*)cwv)[k]);
    L.s0A[t] = a;
  }
  {
    const int rBase = (x == 0) ? NW : 0;
    const int nR = (x == 0) ? GG : 37;
    const float* qet = ws + OFF_QET + (size_t)b * 12800;
    const int r0 = w, r1 = w + 8, r2r = w + 16, r3 = w + 24, r4 = w + 32;
    const bool h0 = r0 < nR, h1 = r1 < nR, h2 = r2r < nR, h3 = r3 < nR, h4 = r4 < nR;
    const int rr0 = rBase + (h0 ? r0 : 0);
    const int rr1 = rBase + (h1 ? r1 : 0);
    const int rr2 = rBase + (h2 ? r2r : 0);
    const int rr3 = rBase + (h3 ? r3 : 0);
    const int rr4 = rBase + (h4 ? r4 : 0);
    float a0 = 0.f, a1 = 0.f, a2 = 0.f, a3 = 0.f, a4 = 0.f;
    for (int j = 0; j < 50; ++j) {
      const float4 qv = ((const float4*)qet)[j * 64 + lane];
      a0 += dot4(*(const float4*)&L.cA[rr0][j * 4], qv);
      a1 += dot4(*(const float4*)&L.cA[rr1][j * 4], qv);
      a2 += dot4(*(const float4*)&L.cA[rr2][j * 4], qv);
      a3 += dot4(*(const float4*)&L.cA[rr3][j * 4], qv);
      a4 += dot4(*(const float4*)&L.cA[rr4][j * 4], qv);
    }
    if (h0) L.sA[rr0][lane] = a0;
    if (h1) L.sA[rr1][lane] = a1;
    if (h2) L.sA[rr2][lane] = a2;
    if (h3) L.sA[rr3][lane] = a3;
    if (h4) L.sA[rr4][lane] = a4;
  }
  __syncthreads();

  // P3: softmaxes into registers (pq: drop s0+bias; pc: drop s1+bias)
  float pv[8];
  const bool rowAct = (t < 216);
  const int grp = t >> 3, j8 = t & 7;
  if (rowAct) {
    if (grp < NW && grp >= L.cntS) {
      #pragma unroll
      for (int k = 0; k < 8; ++k) pv[k] = 0.f;
    } else {
      const int srow = (grp < NW) ? grp : (NW + x);
      #pragma unroll
      for (int k = 0; k < 8; ++k) {
        const int q = j8 * 8 + k;
        const float s = (grp == 26) ? L.s1S[q] : (L.sA[srow][q] + L.s1S[q]);
        pv[k] = (L.qmS[q] > 0) ? s : FNEG;
      }
      float m = pv[0];
      #pragma unroll
      for (int k = 1; k < 8; ++k) m = fmaxf(m, pv[k]);
      m = fmaxf(m, __shfl_xor(m, 1, 64));
      m = fmaxf(m, __shfl_xor(m, 2, 64));
      m = fmaxf(m, __shfl_xor(m, 4, 64));
      float sum = 0.f;
      #pragma unroll
      for (int k = 0; k < 8; ++k) { pv[k] = expf(pv[k] - m); sum += pv[k]; }
      sum += __shfl_xor(sum, 1, 64);
      sum += __shfl_xor(sum, 2, 64);
      sum += __shfl_xor(sum, 4, 64);
      const float inv = 1.f / sum;
      #pragma unroll
      for (int k = 0; k < 8; ++k) pv[k] *= inv;
    }
  }
  float pcv[37];
  const bool colAct = (t >= 256 && t < 320);
  if (colAct) {
    const int qc = t - 256;
    const int cnt = L.cntS;
    float mW = -3.0e38f;
    for (int r = 0; r < NW; ++r)
      if (r < cnt) mW = fmaxf(mW, L.sA[r][qc] + L.s0A[r]);
    float sum = 0.f;
    for (int r = 0; r < NW; ++r) {
      float e = 0.f;
      if (r < cnt) { e = expf(L.sA[r][qc] + L.s0A[r] - mW); sum += e; }
      pcv[r] = e;
    }
    const float inv = (cnt > 0) ? (1.f / sum) : 0.f;
    for (int r = 0; r < NW; ++r) pcv[r] *= inv;
    float mG = -3.0e38f;
    for (int g = 0; g < GG; ++g) mG = fmaxf(mG, L.sA[NW + g][qc] + L.s0A[NW + g]);
    sum = 0.f;
    for (int g = 0; g < GG; ++g) {
      const float e = expf(L.sA[NW + g][qc] + L.s0A[NW + g] - mG);
      pcv[NW + g] = e; sum += e;
    }
    const float invg = 1.f / sum;
    for (int g = 0; g < GG; ++g) pcv[NW + g] *= invg;
  }
  __syncthreads();

  // P4: write pq (pqS + pqT), pc over sA, pad pqT col 27
  if (rowAct) {
    *(float4*)&L.pqS[grp][j8 * 8]     = make_float4(pv[0], pv[1], pv[2], pv[3]);
    *(float4*)&L.pqS[grp][j8 * 8 + 4] = make_float4(pv[4], pv[5], pv[6], pv[7]);
    #pragma unroll
    for (int k = 0; k < 8; ++k) L.pqT[j8 * 8 + k][grp] = pv[k];
  }
  if (colAct) {
    const int qc = t - 256;
    for (int r = 0; r < 37; ++r) L.sA[r][qc] = pcv[r];
  }
  if (t >= 320 && t < 384) L.pqT[t - 320][27] = 0.f;
  __syncthreads();

  // P5: M = pq·pc^T (thread/entry, 2 sweeps) + MTS col pad
  for (int e = t; e < 637; e += 512) {
    int pr, pc;
    if (e < 625) { pr = e / 25; pc = e - pr * 25; }
    else         { pr = 25;     pc = NW + (e - 625); }
    float s = 0.f;
    #pragma unroll 4
    for (int k4 = 0; k4 < 16; ++k4)
      s += dot4(*(const float4*)&L.pqS[pr][k4 * 4], *(const float4*)&L.sA[pc][k4 * 4]);
    if (e < 625) L.MTS[pc][pr] = s; else L.MgS[e - 625] = s;
  }
  if (t < 75) L.MTS[t / 3][25 + t % 3] = 0.f;
  __syncthreads();

  // P6: 2 d-slabs: a-pass (16 cols of pqT) + b2 (16 cols of MTS) + stats
  {
    const int slab = t >> 8, d = t & 255;
    if (d < DD) {
      const int c0 = slab ? 12 : 0;
      float a[16], bb[16];
      #pragma unroll
      for (int k = 0; k < 16; ++k) { a[k] = 0.f; bb[k] = 0.f; }
      const float* qe = q_enc + (size_t)b * QQ * DD + d;
      #pragma unroll 4
      for (int q = 0; q < QQ; ++q) {
        const float vq = qe[(size_t)q * DD];
        const float4 p0 = *(const float4*)&L.pqT[q][c0];
        const float4 p1 = *(const float4*)&L.pqT[q][c0 + 4];
        const float4 p2 = *(const float4*)&L.pqT[q][c0 + 8];
        const float4 p3 = *(const float4*)&L.pqT[q][c0 + 12];
        a[0]+=p0.x*vq; a[1]+=p0.y*vq; a[2]+=p0.z*vq; a[3]+=p0.w*vq;
        a[4]+=p1.x*vq; a[5]+=p1.y*vq; a[6]+=p1.z*vq; a[7]+=p1.w*vq;
        a[8]+=p2.x*vq; a[9]+=p2.y*vq; a[10]+=p2.z*vq; a[11]+=p2.w*vq;
        a[12]+=p3.x*vq; a[13]+=p3.y*vq; a[14]+=p3.z*vq; a[15]+=p3.w*vq;
      }
      #pragma unroll 5
      for (int r2 = 0; r2 < NW; ++r2) {
        const float cv = L.cA[r2][d];
        const float4 m0 = *(const float4*)&L.MTS[r2][c0];
        const float4 m1 = *(const float4*)&L.MTS[r2][c0 + 4];
        const float4 m2 = *(const float4*)&L.MTS[r2][c0 + 8];
        const float4 m3 = *(const float4*)&L.MTS[r2][c0 + 12];
        bb[0]+=m0.x*cv; bb[1]+=m0.y*cv; bb[2]+=m0.z*cv; bb[3]+=m0.w*cv;
        bb[4]+=m1.x*cv; bb[5]+=m1.y*cv; bb[6]+=m1.z*cv; bb[7]+=m1.w*cv;
        bb[8]+=m2.x*cv; bb[9]+=m2.y*cv; bb[10]+=m2.z*cv; bb[11]+=m2.w*cv;
        bb[12]+=m3.x*cv; bb[13]+=m3.y*cv; bb[14]+=m3.z*cv; bb[15]+=m3.w*cv;
      }
      const int cnt = L.cntS;
      float mxa = -3.0e38f, sma = 0.f, mxca = -3.0e38f, smca = 0.f;
      float mxcb = -3.0e38f, smcb = 0.f, aG = 0.f;
      if (slab == 0) {
        #pragma unroll
        for (int k = 0; k < 13; ++k) {          // rows 0..12 = cols 0..12
          if (k < cnt) {
            const float av = a[k], cv = L.cA[k][d];
            mxa = fmaxf(mxa, av); sma += av;
            const float ca = cv * av; mxca = fmaxf(mxca, ca); smca += ca;
            const float cb = cv * bb[k]; mxcb = fmaxf(mxcb, cb); smcb += cb;
          }
        }
      } else {
        #pragma unroll
        for (int k = 1; k < 13; ++k) {          // rows 13..24 = cols 13..24
          const int r = 12 + k;
          if (r < cnt) {
            const float av = a[k], cv = L.cA[r][d];
            mxa = fmaxf(mxa, av); sma += av;
            const float ca = cv * av; mxca = fmaxf(mxca, ca); smca += ca;
            const float cb = cv * bb[k]; mxcb = fmaxf(mxcb, cb); smcb += cb;
          }
        }
        aG = a[13];                              // col 25 = gap-row-x
        const float ac = a[14];                  // col 26 = const row
        mxa = fmaxf(mxa, ac);
        sma += (float)(LL - cnt) * ac;
      }
      float* sp = &L.statS[slab][d * 7];
      sp[0] = mxa; sp[1] = sma; sp[2] = mxca; sp[3] = smca;
      sp[4] = mxcb; sp[5] = smcb; sp[6] = aG;
    }
  }
  __syncthreads();

  // P7: merge stats + gap features + att part (t<200), then block reduce
  float acc = 0.f;
  const float* wa  = x ? wA  : wAs;
  const float* wm  = x ? wM  : wMs;
  const float* wa2 = x ? wA2 : wA2s;
  if (t < DD) {
    const int d = t;
    const float* s0p = &L.statS[0][d * 7];
    const float* s1p = &L.statS[1][d * 7];
    const float mxa  = fmaxf(s0p[0], s1p[0]);
    const float sma  = s0p[1] + s1p[1];
    const float mxca = fmaxf(0.f, fmaxf(s0p[2], s1p[2]));
    const float smca = s0p[3] + s1p[3];
    const float mxcb = fmaxf(0.f, fmaxf(s0p[4], s1p[4]));
    const float smcb = s0p[5] + s1p[5];
    const float aG   = s1p[6];
    const float cg = L.cA[NW + x][d];
    float b2G = 0.f;
    #pragma unroll
    for (int g = 0; g < GG; ++g) b2G += L.MgS[g] * L.cA[NW + g][d];
    acc += cg * (wa2[d] + wm[d]) + aG * wa2[DD + d]
         + cg * aG * wa2[2 * DD + d] + cg * b2G * wa2[3 * DD + d];
    if (x > 0) {
      const int cnt = L.cntS;
      const float invc = 1.f / (float)cnt;
      float mxc = 0.f, smc = 0.f;
      #pragma unroll
      for (int r = 0; r < NW; ++r) {
        if (r < cnt) { const float cv = L.cA[r][d]; mxc = fmaxf(mxc, cv); smc += cv; }
      }
      acc += mxc * (wm[DD + d] + wa2[AD + d]) + smc * invc * (wm[2 * DD + d] + wa2[2 * AD + d]);
      acc += mxa * wa2[AD + DD + d]      + sma  * invc * wa2[2 * AD + DD + d];
      acc += mxca * wa2[AD + 2 * DD + d] + smca * invc * wa2[2 * AD + 2 * DD + d];
      acc += mxcb * wa2[AD + 3 * DD + d] + smcb * invc * wa2[2 * AD + 3 * DD + d];
    }
    // att: gap-row dot + (x>0) window pool, float4 column t
    const float4 w0 = ((const float4*)wa)[t];
    const float4 ar = ((const float4*)(att + ((size_t)b * LL + L.gidS) * AD))[t];
    acc += dot4(ar, w0);
    if (x > 0) {
      const float4 w1 = ((const float4*)(wa + AD))[t];
      const float4 w2 = ((const float4*)(wa + 2 * AD))[t];
      float4 mx = make_float4(0.f, 0.f, 0.f, 0.f);
      float4 sm = make_float4(0.f, 0.f, 0.f, 0.f);
      const int cnt = L.cntS;
      for (int r = 0; r < NW; ++r) {
        if (r < cnt) {
          const float4 v = ((const float4*)(att + ((size_t)b * LL + L.rowsS[r]) * AD))[t];
          mx = max4(mx, v); sm = add4(sm, v);
        }
      }
      const float invc = 1.f / (float)cnt;
      acc += dot4(mx, w1) + invc * dot4(sm, w2);
    }
  }
  const float wsum = wave_sum(acc);
  if (lane == 0) L.red[w] = wsum;
  __syncthreads();
  if (t == 0) {
    float s = 0.f;
    #pragma unroll
    for (int i2 = 0; i2 < 8; ++i2) s += L.red[i2];
    if (x == 0) ws[OFF_PART + b] = s;
    else out[b * GG + x] = s + bA[0] + bM[0] + bA2[0];
  }
}

// ============================================================================
// k_finish: pool0 dots + x==0 partial + biases -> out[b][0]. grid 16 x 256.
// ============================================================================
__global__ __launch_bounds__(256) void k_finish(const int* __restrict__ mask,
    const float* __restrict__ wAs, const float* __restrict__ bAs,
    const float* __restrict__ wMs, const float* __restrict__ bMs,
    const float* __restrict__ bA2s,
    const float* __restrict__ ws, float* __restrict__ out) {
  const int b = blockIdx.x, t = threadIdx.x;
  __shared__ float red[4];
  __shared__ float inv0S;
  int cm = 0;
  for (int l = t; l < LL; l += 256) cm += (mask[(size_t)b * LL + l] > 0) ? 1 : 0;
  const float cf = wave_sum((float)cm);
  if ((t & 63) == 0) red[t >> 6] = cf;
  __syncthreads();
  if (t == 0) inv0S = 1.f / (red[0] + red[1] + red[2] + red[3]);
  __syncthreads();
  const float inv0 = inv0S;
  float acc = 0.f;
  if (t < 200) {
    float4 m = ((const float4*)(ws + OFF_PAM))[(size_t)b * 32 * 200 + t];
    float4 s = ((const float4*)(ws + OFF_PAS))[(size_t)b * 32 * 200 + t];
    for (int ch = 1; ch < 32; ++ch) {
      m = max4(m, ((const float4*)(ws + OFF_PAM))[((size_t)b * 32 + ch) * 200 + t]);
      s = add4(s, ((const float4*)(ws + OFF_PAS))[((size_t)b * 32 + ch) * 200 + t]);
    }
    acc += dot4(m, ((const float4*)(wAs + AD))[t]) + inv0 * dot4(s, ((const float4*)(wAs + 2 * AD))[t]);
  }
  if (t < 50) {
    float4 m = ((const float4*)(ws + OFF_PMM))[(size_t)b * 4 * 50 + t];
    float4 s = ((const float4*)(ws + OFF_PMS))[(size_t)b * 4 * 50 + t];
    #pragma unroll
    for (int ch = 1; ch < 4; ++ch) {
      m = max4(m, ((const float4*)(ws + OFF_PMM))[((size_t)b * 4 + ch) * 50 + t]);
      s = add4(s, ((const float4*)(ws + OFF_PMS))[((size_t)b * 4 + ch) * 50 + t]);
    }
    acc += dot4(m, ((const float4*)(wMs + DD))[t]) + inv0 * dot4(s, ((const float4*)(wMs + 2 * DD))[t]);
  }
  __syncthreads();
  const float tot = wave_sum(acc);
  if ((t & 63) == 0) red[t >> 6] = tot;
  __syncthreads();
  if (t == 0)
    out[b * GG] = red[0] + red[1] + red[2] + red[3] + ws[OFF_PART + b]
                + bAs[0] + bMs[0] + bA2s[0];
}

// ============================================================================
extern "C" void kernel_launch(void* const* d_in, const int* in_sizes, int n_in,
                              void* d_out, int out_size, void* d_ws, size_t ws_size,
                              hipStream_t stream) {
  (void)in_sizes; (void)n_in; (void)out_size; (void)ws_size;
  const float* att    = (const float*)d_in[0];
  const float* mod    = (const float*)d_in[1];
  const int*   gaps   = (const int*)  d_in[2];
  const int*   mask   = (const int*)  d_in[3];
  const float* q_enc  = (const float*)d_in[4];
  const int*   q_mask = (const int*)  d_in[5];
  const float* cwv    = (const float*)d_in[6];
  const float* qwv    = (const float*)d_in[7];
  const float* cqw    = (const float*)d_in[8];
  const float* wA     = (const float*)d_in[10];
  const float* bA     = (const float*)d_in[11];
  const float* wM     = (const float*)d_in[12];
  const float* bM     = (const float*)d_in[13];
  const float* wA2    = (const float*)d_in[14];
  const float* bA2    = (const float*)d_in[15];
  const float* wAs    = (const float*)d_in[16];
  const float* bAs    = (const float*)d_in[17];
  const float* wMs    = (const float*)d_in[18];
  const float* bMs    = (const float*)d_in[19];
  const float* wA2s   = (const float*)d_in[20];
  const float* bA2s   = (const float*)d_in[21];
  float* out = (float*)d_out;
  float* ws  = (float*)d_ws;

  hipLaunchKernelGGL(k_pre, dim3(4, 16), dim3(256), 0, stream, q_enc, qwv, cqw, ws);
  hipLaunchKernelGGL(k_uni, dim3(768), dim3(512), 0, stream,
                     att, mod, gaps, mask, q_enc, q_mask, cwv,
                     wA, bA, wM, bM, wA2, bA2, wAs, wMs, wA2s, ws, out);
  hipLaunchKernelGGL(k_finish, dim3(16), dim3(256), 0, stream,
                     mask, wAs, bAs, wMs, bMs, bA2s, ws, out);
}